// Round 2
// 824.378 us; speedup vs baseline: 1.0248x; 1.0248x over previous
//
#include <hip/hip_runtime.h>

// ============================================================================
// CascadeRCNN: 3-stage cascade of {pyramid ROI-align -> fc1 -> fc2 -> heads}
//  - Stages 0/1: SPLIT bf16 (hi+lo, 3 MFMA products) fc1/fc2 -> fp32-accurate
//    reg deltas (they feed the discontinuous pyramid-level select).
//  - Stage 2: fc1 for heads 0,1,2 as ONE fused GEMM M=1024 x N=3072 on the
//    256x256x64 4-phase-per-tile kernel (R6); fc2/cls stay on the 128^2 kernel.
//  - R6 FIX of R5's broken pipeline: R5 staged two K-tiles into one buffer
//    (dst ignored kt) and read the same 64-wide tile for both "halves".
//    Now: 1 K-tile/iter, buf = tile parity. Reads of buf in P1-P3; all 8
//    stage loads for tile i+2 go in P4 AFTER P3's end-barrier (WAR-safe by
//    barrier proof, not timing). Counted vmcnt(8) at P4 (never 0 in steady
//    state); barrier after vmcnt makes the per-wave count globally valid.
//    setprio(1) around MFMA quadrants, sched_barrier(0) after lgkmcnt(0).
//  - R4: split-K S01=8, S2=4 sweet spot (deeper split thrashed L2).
// ============================================================================

#define BM 128
#define BN 128
#define BK 32
#define K1 12544
#define MPAD 1024
#define NROI 1000

typedef __bf16 bf16_t;
typedef bf16_t bf16x8 __attribute__((ext_vector_type(8)));
typedef float f32x4 __attribute__((ext_vector_type(4)));
typedef float f32x2 __attribute__((ext_vector_type(2)));
typedef unsigned short u16x4 __attribute__((ext_vector_type(4)));
typedef unsigned short u16x2 __attribute__((ext_vector_type(2)));

__device__ __forceinline__ unsigned short f2bf(float x) {
  unsigned u = __float_as_uint(x);
  return (unsigned short)((u + 0x7fffu + ((u >> 16) & 1u)) >> 16);
}
__device__ __forceinline__ float bf2f(unsigned short h) {
  return __uint_as_float(((unsigned)h) << 16);
}

__device__ __forceinline__ void gld_lds16(const void* g, void* l) {
  __builtin_amdgcn_global_load_lds(
      (__attribute__((address_space(1))) void*)g,
      (__attribute__((address_space(3))) void*)l, 16, 0, 0);
}

// ---------------------------------------------------------------------------
// OLD GEMM (128x128x32, 4 waves): kept for split-precision stages 0/1 and the
// small stage-2 fc2/cls GEMMs. C_part[s][h][m][n] = A[h](1024 x K)*B[h]^T.
// ---------------------------------------------------------------------------
template <bool SPLIT>
__global__ __launch_bounds__(256, 4)
void gemm_bf16(const unsigned short* __restrict__ Ah,
               const unsigned short* __restrict__ Al,
               long long strideA_head,
               const unsigned short* __restrict__ Bh,
               const unsigned short* __restrict__ Bl,
               long long strideB_head,
               float* __restrict__ Cpart,
               int Nh, int K, int kcSteps)
{
  __shared__ __align__(16) unsigned short sAh[BM * BK];
  __shared__ __align__(16) unsigned short sBh[BN * BK];
  __shared__ __align__(16) unsigned short sAl[SPLIT ? BM * BK : 8];
  __shared__ __align__(16) unsigned short sBl[SPLIT ? BN * BK : 8];

  const int t = threadIdx.x;
  const int ntile = Nh / BN;
  const int bm = blockIdx.x / ntile;
  const int bn = blockIdx.x % ntile;
  const int s = blockIdx.y;
  const int h = blockIdx.z;
  const int H = gridDim.z;

  const unsigned short* Ab = Ah + (size_t)h * strideA_head + (size_t)bm * BM * K;
  const unsigned short* Bb = Bh + (size_t)h * strideB_head + (size_t)bn * BN * K;
  const unsigned short* Alb = SPLIT ? (Al + (size_t)h * strideA_head + (size_t)bm * BM * K) : (const unsigned short*)0;
  const unsigned short* Blb = SPLIT ? (Bl + (size_t)h * strideB_head + (size_t)bn * BN * K) : (const unsigned short*)0;

  int k0 = s * kcSteps * BK;
  int k1 = min(K, k0 + kcSteps * BK);

  const int srow = t >> 2;
  const int gsw = ((t & 3) ^ ((srow >> 1) & 3)) * 8;
  const int lane = t & 63;
  const int wv = t >> 6;
  const int wm = (wv >> 1) * 64;
  const int wn = (wv & 1) * 64;
  const int lr = lane & 15;
  const int q = lane >> 4;
  const int sw = (lr >> 1) & 3;
  const int cA = (q ^ sw) * 8;

  f32x4 acc[4][4];
  const f32x4 z = {0.f, 0.f, 0.f, 0.f};
#pragma unroll
  for (int i = 0; i < 4; ++i)
#pragma unroll
    for (int j = 0; j < 4; ++j) acc[i][j] = z;

  for (int kk = k0; kk < k1; kk += BK) {
#pragma unroll
    for (int j = 0; j < 2; ++j) {
      int row = j * 64 + srow;
      gld_lds16(Ab + (size_t)row * K + kk + gsw, (char*)sAh + j * 4096 + t * 16);
      gld_lds16(Bb + (size_t)row * K + kk + gsw, (char*)sBh + j * 4096 + t * 16);
      if constexpr (SPLIT) {
        gld_lds16(Alb + (size_t)row * K + kk + gsw, (char*)sAl + j * 4096 + t * 16);
        gld_lds16(Blb + (size_t)row * K + kk + gsw, (char*)sBl + j * 4096 + t * 16);
      }
    }
    __syncthreads();

    bf16x8 af[4], bfr[4];
#pragma unroll
    for (int i = 0; i < 4; ++i) af[i] = *(const bf16x8*)&sAh[(wm + i * 16 + lr) * BK + cA];
#pragma unroll
    for (int j = 0; j < 4; ++j) bfr[j] = *(const bf16x8*)&sBh[(wn + j * 16 + lr) * BK + cA];
#pragma unroll
    for (int i = 0; i < 4; ++i)
#pragma unroll
      for (int j = 0; j < 4; ++j)
        acc[i][j] = __builtin_amdgcn_mfma_f32_16x16x32_bf16(af[i], bfr[j], acc[i][j], 0, 0, 0);

    if constexpr (SPLIT) {
      bf16x8 al[4], bl[4];
#pragma unroll
      for (int i = 0; i < 4; ++i) al[i] = *(const bf16x8*)&sAl[(wm + i * 16 + lr) * BK + cA];
#pragma unroll
      for (int j = 0; j < 4; ++j) bl[j] = *(const bf16x8*)&sBl[(wn + j * 16 + lr) * BK + cA];
#pragma unroll
      for (int i = 0; i < 4; ++i)
#pragma unroll
        for (int j = 0; j < 4; ++j) {
          acc[i][j] = __builtin_amdgcn_mfma_f32_16x16x32_bf16(af[i], bl[j], acc[i][j], 0, 0, 0);
          acc[i][j] = __builtin_amdgcn_mfma_f32_16x16x32_bf16(al[i], bfr[j], acc[i][j], 0, 0, 0);
        }
    }
    __syncthreads();
  }

  float* Cb = Cpart + ((size_t)(s * H + h) * MPAD + (size_t)bm * BM) * Nh + (size_t)bn * BN;
#pragma unroll
  for (int i = 0; i < 4; ++i)
#pragma unroll
    for (int j = 0; j < 4; ++j)
#pragma unroll
      for (int r = 0; r < 4; ++r) {
        int m = wm + i * 16 + q * 4 + r;
        int n = wn + j * 16 + lr;
        Cb[(size_t)m * Nh + n] = acc[i][j][r];
      }
}

// ---------------------------------------------------------------------------
// NEW (R6): 256x256 tile, BK=64, 8 waves (2Mx4N), 4 phases per K-tile,
// double-buffered (buf = tile&1), counted vmcnt. A [1024][K] bf16,
// B [Ntot][K] bf16 (B^T), Cpart [S][1024][Ntot] fp32, split-K by 64-tiles.
// LDS (dynamic 131072B): buf b at b*65536: A tile 32768B then B tile 32768B.
// Swizzle: physical 16B-group pg at row r holds logical group pg ^ (r&7),
// staged via pre-swizzled GLOBAL source (m173 pattern), read with same XOR.
//
// Race-free schedule proof sketch:
//   reads of buf: P1 (A0+B0), P2 (B1), P3 (A1). Each wave's P3 lgkmcnt(0)
//   covers all its reads; P3 END barrier => ALL waves' reads complete.
//   P4 (after that barrier) issues the 8 stage loads for tile i+2 -> buf,
//   then vmcnt(8) (tile i+1's 8 loads landed; i+2's 8 remain in flight),
//   then barrier (makes per-wave vmcnt globally valid) => next tile's P1
//   reads of buf^1 are RAW-safe.
// ---------------------------------------------------------------------------
#define DS_A(XB, MH) do { \
    rA[0][0]=lda_f(XB,(MH)*4+0,0); rA[0][1]=lda_f(XB,(MH)*4+0,1); \
    rA[1][0]=lda_f(XB,(MH)*4+1,0); rA[1][1]=lda_f(XB,(MH)*4+1,1); \
    rA[2][0]=lda_f(XB,(MH)*4+2,0); rA[2][1]=lda_f(XB,(MH)*4+2,1); \
    rA[3][0]=lda_f(XB,(MH)*4+3,0); rA[3][1]=lda_f(XB,(MH)*4+3,1); } while(0)

#define DS_B(XB, NH) do { \
    rB[(NH)*2+0][0]=ldb_f(XB,(NH)*2+0,0); rB[(NH)*2+0][1]=ldb_f(XB,(NH)*2+0,1); \
    rB[(NH)*2+1][0]=ldb_f(XB,(NH)*2+1,0); rB[(NH)*2+1][1]=ldb_f(XB,(NH)*2+1,1); } while(0)

// Q(MH,NH): 16 MFMAs into acc[MH*4+ii][NH*2+jj]; rA holds the MH half.
#define MFMA_Q(MH, NH) do { \
  _Pragma("unroll") \
  for (int ii = 0; ii < 4; ++ii) { \
    _Pragma("unroll") \
    for (int jj = 0; jj < 2; ++jj) { \
      acc[(MH)*4+ii][(NH)*2+jj] = __builtin_amdgcn_mfma_f32_16x16x32_bf16(rA[ii][0], rB[(NH)*2+jj][0], acc[(MH)*4+ii][(NH)*2+jj], 0, 0, 0); \
      acc[(MH)*4+ii][(NH)*2+jj] = __builtin_amdgcn_mfma_f32_16x16x32_bf16(rA[ii][1], rB[(NH)*2+jj][1], acc[(MH)*4+ii][(NH)*2+jj], 0, 0, 0); \
    } } } while(0)

#define PHASE_SYNC() do { \
  __builtin_amdgcn_s_barrier(); \
  asm volatile("s_waitcnt lgkmcnt(0)" ::: "memory"); \
  __builtin_amdgcn_sched_barrier(0); } while(0)

#define PHASE_END() do { \
  __builtin_amdgcn_s_setprio(0); \
  __builtin_amdgcn_s_barrier(); } while(0)

__global__ __launch_bounds__(512, 2)
void gemm256_bf16(const unsigned short* __restrict__ A,
                  const unsigned short* __restrict__ B,
                  float* __restrict__ Cpart,
                  int Ntot, int K, int tilesTotal)
{
  extern __shared__ char lds[];
  const int t = threadIdx.x;
  const int ntile = Ntot >> 8;
  const int bm = blockIdx.x / ntile;
  const int bn = blockIdx.x % ntile;
  const int s = blockIdx.y;
  const int S = gridDim.y;
  const int qp = tilesTotal / S, rp = tilesTotal % S;
  const int t0 = s * qp + (s < rp ? s : rp);   // first K-tile of this split
  const int np = qp + (s < rp ? 1 : 0);        // #K-tiles in this split

  const unsigned short* Ab = A + (size_t)bm * 256 * K;
  const unsigned short* Bb = B + (size_t)bn * 256 * K;

  // staging: thread t writes LDS slot (row=srow[+64], pg=t&7); logical group
  // there must be (t&7)^(srow&7) -> pre-swizzled global source column.
  const int srow = t >> 3;                       // 0..63
  const int sgrp = ((t & 7) ^ (srow & 7)) << 3;  // source col group (elems)

  const int lane = t & 63;
  const int wv = t >> 6;
  const int wm = (wv >> 2) << 7;  // 0 / 128
  const int wn = (wv & 3) << 6;   // 0 / 64 / 128 / 192
  const int lr = lane & 15;
  const int q = lane >> 4;

  f32x4 acc[8][4];
  const f32x4 z = {0.f, 0.f, 0.f, 0.f};
#pragma unroll
  for (int i = 0; i < 8; ++i)
#pragma unroll
    for (int j = 0; j < 4; ++j) acc[i][j] = z;

  bf16x8 rA[4][2], rB[4][2];

  // stage one full K-tile (A 256x64 + B 256x64 = 8 gld_lds16) into xbuf
  auto stage_tile = [&](int xbuf, int kt) {
    const size_t col = ((size_t)(t0 + kt) << 6) + sgrp;
#pragma unroll
    for (int u = 0; u < 4; ++u) {
      const unsigned short* src = (u < 2) ? Ab : Bb;
      const int rbase = ((u & 1) << 7) + srow;
      char* dst = lds + xbuf * 65536 + ((u & 2) << 14) + ((u & 1) << 14) + t * 16;
      gld_lds16(src + (size_t)rbase * K + col, dst);
      gld_lds16(src + (size_t)(rbase + 64) * K + col, dst + 8192);
    }
  };

  auto lda_f = [&](int xbuf, int i, int ks) -> bf16x8 {
    const int row = wm + (i << 4) + lr;
    const int pg = (ks * 4 + q) ^ (row & 7);
    return *(const bf16x8*)(lds + xbuf * 65536 + row * 128 + pg * 16);
  };
  auto ldb_f = [&](int xbuf, int j, int ks) -> bf16x8 {
    const int row = wn + (j << 4) + lr;
    const int pg = (ks * 4 + q) ^ (row & 7);
    return *(const bf16x8*)(lds + xbuf * 65536 + 32768 + row * 128 + pg * 16);
  };

  // prologue: tile 0 -> buf0, tile 1 -> buf1
  stage_tile(0, 0);
  if (np > 1) {
    stage_tile(1, 1);
    asm volatile("s_waitcnt vmcnt(8)" ::: "memory");  // tile 0 landed
  } else {
    asm volatile("s_waitcnt vmcnt(0)" ::: "memory");
  }
  __builtin_amdgcn_s_barrier();

  for (int i = 0; i < np; ++i) {
    const int buf = i & 1;
    const bool st = (i + 2 < np);
    // ---- P1: 12 ds_reads (A half 0 + B group 0)
    DS_A(buf, 0);
    DS_B(buf, 0);
    PHASE_SYNC();
    __builtin_amdgcn_s_setprio(1);
    MFMA_Q(0, 0);
    PHASE_END();
    // ---- P2: 4 ds_reads (B group 1)
    DS_B(buf, 1);
    PHASE_SYNC();
    __builtin_amdgcn_s_setprio(1);
    MFMA_Q(0, 1);
    PHASE_END();
    // ---- P3: 8 ds_reads (A half 1; overwrites rA, Q(0,*) done)
    DS_A(buf, 1);
    PHASE_SYNC();
    __builtin_amdgcn_s_setprio(1);
    MFMA_Q(1, 0);
    PHASE_END();
    // ---- P4: stage tile i+2 into buf (all reads of buf proven complete by
    //          P3 END barrier), counted vmcnt, barrier, last quadrant.
    if (st) {
      stage_tile(buf, i + 2);
      asm volatile("s_waitcnt vmcnt(8)" ::: "memory");  // tile i+1 landed
    } else {
      asm volatile("s_waitcnt vmcnt(0)" ::: "memory");  // tail drain
    }
    __builtin_amdgcn_s_barrier();
    __builtin_amdgcn_sched_barrier(0);
    __builtin_amdgcn_s_setprio(1);
    MFMA_Q(1, 1);
    __builtin_amdgcn_s_setprio(0);
  }

  float* Cb = Cpart + (size_t)s * MPAD * Ntot +
              (size_t)(bm * 256 + wm) * Ntot + bn * 256 + wn;
#pragma unroll
  for (int i = 0; i < 8; ++i)
#pragma unroll
    for (int j = 0; j < 4; ++j)
#pragma unroll
      for (int r = 0; r < 4; ++r)
        Cb[(size_t)(i * 16 + q * 4 + r) * Ntot + j * 16 + lr] = acc[i][j][r];
}

// ---------------------------------------------------------------------------
// Epilogue (x4 vectorized): v = relu(sum_s partial + bias), emit bf16 hi[,lo].
// ---------------------------------------------------------------------------
__global__ __launch_bounds__(256)
void epilogue_kernel(const float* __restrict__ Cpart, int S, int H, int Nh,
                     const float* __restrict__ bias,
                     unsigned short* __restrict__ ohi,
                     unsigned short* __restrict__ olo, int flags)
{
  size_t total = (size_t)H * MPAD * Nh;
  size_t idx = ((size_t)blockIdx.x * 256 + threadIdx.x) * 4;
  if (idx >= total) return;
  int n = (int)(idx % Nh);
  int h = (int)(idx / ((size_t)MPAD * Nh));
  f32x4 v = *(const f32x4*)&bias[(size_t)h * Nh + n];
  for (int s = 0; s < S; ++s) v += *(const f32x4*)&Cpart[(size_t)s * total + idx];
  u16x4 hi, lo;
#pragma unroll
  for (int j = 0; j < 4; ++j) {
    float x = fmaxf(v[j], 0.f);
    hi[j] = f2bf(x);
    lo[j] = f2bf(x - bf2f(hi[j]));
  }
  *(u16x4*)&ohi[idx] = hi;
  if (flags & 4) *(u16x4*)&olo[idx] = lo;
}

// Epilogue for stage-2 fused fc1 (N=3072): partials [s][1024][3072],
// de-interleave into h1_hi[h][1024][1024]. bias = fc1_b (3x1024 contiguous).
__global__ __launch_bounds__(256)
void epilogue_fc1_s2(const float* __restrict__ Cpart, int S,
                     const float* __restrict__ bias,
                     unsigned short* __restrict__ ohi)
{
  const size_t total = (size_t)MPAD * 3072;
  size_t idx = ((size_t)blockIdx.x * 256 + threadIdx.x) * 4;
  if (idx >= total) return;
  int n = (int)(idx % 3072);
  int m = (int)(idx / 3072);
  f32x4 v = *(const f32x4*)&bias[n];
  for (int s = 0; s < S; ++s) v += *(const f32x4*)&Cpart[(size_t)s * total + idx];
  u16x4 hi;
#pragma unroll
  for (int j = 0; j < 4; ++j) hi[j] = f2bf(fmaxf(v[j], 0.f));
  int h = n >> 10;
  *(u16x4*)&ohi[((size_t)h * MPAD + m) * 1024 + (n & 1023)] = hi;
}

// ---------------------------------------------------------------------------
// Transpose + fp32->bf16 hi/lo: W[H][K][N] -> T[H][N][K].
// ---------------------------------------------------------------------------
__global__ __launch_bounds__(256)
void transpose_convert(const float* __restrict__ W,
                       unsigned short* __restrict__ Thi,
                       unsigned short* __restrict__ Tlo,
                       int K, int N, int loHeads)
{
  __shared__ float tile[32][260];
  int kb = blockIdx.x * 256;
  int nb = blockIdx.y * 32;
  int h = blockIdx.z;
  const float* Wb = W + (size_t)h * K * N + (size_t)kb * N + nb;
  int tn = threadIdx.x & 31;
  int tk = threadIdx.x >> 5;
#pragma unroll
  for (int i = 0; i < 32; ++i) {
    int k = tk + i * 8;
    tile[tn][k] = Wb[(size_t)k * N + tn];
  }
  __syncthreads();
  bool wlo = h < loHeads;
  int l = threadIdx.x & 63;
  int ng = threadIdx.x >> 6;
  size_t ob = (size_t)h * N * K + (size_t)nb * K + kb;
#pragma unroll
  for (int i = 0; i < 8; ++i) {
    int n = ng + i * 4;
    f32x4 v = *(const f32x4*)&tile[n][4 * l];
    u16x4 hi;
#pragma unroll
    for (int j = 0; j < 4; ++j) hi[j] = f2bf(v[j]);
    *(u16x4*)&Thi[ob + (size_t)n * K + 4 * l] = hi;
    if (wlo) {
      u16x4 lo;
#pragma unroll
      for (int j = 0; j < 4; ++j) lo[j] = f2bf(v[j] - bf2f(hi[j]));
      *(u16x4*)&Tlo[ob + (size_t)n * K + 4 * l] = lo;
    }
  }
}

// cls_w (3,1024,81) -> w3t (3,128,1024) bf16, rows 81..127 zero. grid (128,3).
__global__ void transpose_cls(const float* __restrict__ W, unsigned short* __restrict__ T)
{
  int n = blockIdx.x, h = blockIdx.y, t = threadIdx.x;
  size_t ob = ((size_t)h * 128 + n) * 1024;
  if (n < 81) {
    for (int k = t; k < 1024; k += 256)
      T[ob + k] = f2bf(W[((size_t)h * 1024 + k) * 81 + n]);
  } else {
    for (int k = t; k < 1024; k += 256) T[ob + k] = 0;
  }
}

// ---------------------------------------------------------------------------
// Pyramid ROI-align: one block per roi; 64 channel-quads x 4 position groups.
// ---------------------------------------------------------------------------
__global__ void roi_align_kernel(const float* __restrict__ rois,
                                 const float* __restrict__ P2, const float* __restrict__ P3,
                                 const float* __restrict__ P4, const float* __restrict__ P5,
                                 unsigned short* __restrict__ phi,
                                 unsigned short* __restrict__ plo, int writeLo)
{
  int m = blockIdx.x;
  int t = threadIdx.x;
  int c = (t & 63) * 4;
  int pg = t >> 6;  // 0..3
  const float* rp = rois + m * 4;
  float y1 = rp[0], x1 = rp[1], y2 = rp[2], x2 = rp[3];
  float hh = y2 - y1, ww = x2 - x1;
  float a = sqrtf(fmaxf(hh * ww, 1e-6f)) / 224.0f;
  float lvl = floorf(4.0f + log2f(a));
  lvl = fminf(fmaxf(lvl, 2.0f), 5.0f);
  int i = (int)lvl - 2;
  const float* f = (i == 0) ? P2 : (i == 1) ? P3 : (i == 2) ? P4 : P5;
  int H = 256 >> i;
  float stride = (float)(4 << i);
  float sy1 = y1 / stride, sx1 = x1 / stride;
  float dy = y2 / stride - sy1, dx = x2 / stride - sx1;
  size_t base = (size_t)m * K1 + c;
  for (int p = pg; p < 49; p += 4) {
    int py = p / 7, px = p % 7;
    float ys = sy1 + ((py + 0.5f) / 7.0f) * dy;
    float xs = sx1 + ((px + 0.5f) / 7.0f) * dx;
    float y0f = fminf(fmaxf(floorf(ys), 0.0f), (float)(H - 1));
    float x0f = fminf(fmaxf(floorf(xs), 0.0f), (float)(H - 1));
    int y0 = (int)y0f, x0 = (int)x0f;
    int y1i = min(y0 + 1, H - 1), x1i = min(x0 + 1, H - 1);
    float wy = fminf(fmaxf(ys - y0f, 0.0f), 1.0f);
    float wx = fminf(fmaxf(xs - x0f, 0.0f), 1.0f);
    f32x4 v00 = *(const f32x4*)(f + ((size_t)y0 * H + x0) * 256 + c);
    f32x4 v01 = *(const f32x4*)(f + ((size_t)y0 * H + x1i) * 256 + c);
    f32x4 v10 = *(const f32x4*)(f + ((size_t)y1i * H + x0) * 256 + c);
    f32x4 v11 = *(const f32x4*)(f + ((size_t)y1i * H + x1i) * 256 + c);
    float w00 = (1.f - wy) * (1.f - wx), w01 = (1.f - wy) * wx;
    float w10 = wy * (1.f - wx), w11 = wy * wx;
    f32x4 v = v00 * w00 + v01 * w01 + v10 * w10 + v11 * w11;
    u16x4 hi;
#pragma unroll
    for (int j = 0; j < 4; ++j) hi[j] = f2bf(v[j]);
    *(u16x4*)&phi[base + p * 256] = hi;
    if (writeLo) {
      u16x4 lo;
#pragma unroll
      for (int j = 0; j < 4; ++j) lo[j] = f2bf(v[j] - bf2f(hi[j]));
      *(u16x2*)&plo[base + p * 256] = *(u16x2*)&lo;  // first 2
      *(u16x2*)&plo[base + p * 256 + 2] = *((u16x2*)&lo + 1);
    }
  }
}

// ---------------------------------------------------------------------------
// FUSED fc2-epilogue + reg head + delta2bbox (stages 0/1).
// ---------------------------------------------------------------------------
__global__ void reg_delta_kernel(const float* __restrict__ Cpart, int S,
                                 const float* __restrict__ fb,
                                 const float* __restrict__ rw, const float* __restrict__ rb,
                                 const float* __restrict__ rin, float* __restrict__ rout)
{
  int m = blockIdx.x, t = threadIdx.x;
  float s0 = 0, s1 = 0, s2 = 0, s3 = 0;
  for (int n = t; n < 1024; n += 256) {
    float v = fb[n];
    for (int s = 0; s < S; ++s) v += Cpart[((size_t)s * 1024 + m) * 1024 + n];
    v = fmaxf(v, 0.f);
    const float* w = rw + (size_t)n * 4;
    s0 += v * w[0]; s1 += v * w[1]; s2 += v * w[2]; s3 += v * w[3];
  }
#pragma unroll
  for (int o = 32; o > 0; o >>= 1) {
    s0 += __shfl_xor(s0, o, 64);
    s1 += __shfl_xor(s1, o, 64);
    s2 += __shfl_xor(s2, o, 64);
    s3 += __shfl_xor(s3, o, 64);
  }
  __shared__ float part[4][4];
  int w = t >> 6;
  if ((t & 63) == 0) { part[w][0] = s0; part[w][1] = s1; part[w][2] = s2; part[w][3] = s3; }
  __syncthreads();
  if (t == 0) {
    float d0 = (part[0][0] + part[1][0] + part[2][0] + part[3][0] + rb[0]) * 0.1f;
    float d1 = (part[0][1] + part[1][1] + part[2][1] + part[3][1] + rb[1]) * 0.1f;
    float d2 = (part[0][2] + part[1][2] + part[2][2] + part[3][2] + rb[2]) * 0.2f;
    float d3 = (part[0][3] + part[1][3] + part[2][3] + part[3][3] + rb[3]) * 0.2f;
    const float* r = rin + m * 4;
    float y1 = r[0], x1 = r[1], y2 = r[2], x2 = r[3];
    float h = y2 - y1, wd = x2 - x1;
    float cy = y1 + 0.5f * h + d0 * h;
    float cx = x1 + 0.5f * wd + d1 * wd;
    float nh = h * expf(d2);
    float nw = wd * expf(d3);
    float* ro = rout + m * 4;
    ro[0] = fminf(fmaxf(cy - 0.5f * nh, 0.f), 1024.f);
    ro[1] = fminf(fmaxf(cx - 0.5f * nw, 0.f), 1024.f);
    ro[2] = fminf(fmaxf(cy + 0.5f * nh, 0.f), 1024.f);
    ro[3] = fminf(fmaxf(cx + 0.5f * nw, 0.f), 1024.f);
  }
}

// ---------------------------------------------------------------------------
// FUSED cls-epilogue + softmax + 3-head average.
// ---------------------------------------------------------------------------
__global__ void softmax_avg_kernel(const float* __restrict__ Cpart, int S,
                                   const float* __restrict__ cls_b,
                                   float* __restrict__ out)
{
  int m = blockIdx.x, t = threadIdx.x;
  __shared__ float sh[128];
  float pacc = 0.0f;
  for (int h = 0; h < 3; ++h) {
    float x = -3.0e38f;
    if (t < 81) {
      x = cls_b[h * 81 + t];
      for (int s = 0; s < S; ++s)
        x += Cpart[((size_t)(s * 3 + h) * 1024 + m) * 128 + t];
    }
    sh[t] = x; __syncthreads();
    for (int o = 64; o > 0; o >>= 1) { if (t < o) sh[t] = fmaxf(sh[t], sh[t + o]); __syncthreads(); }
    float mx = sh[0]; __syncthreads();
    float e = (t < 81) ? expf(x - mx) : 0.0f;
    sh[t] = e; __syncthreads();
    for (int o = 64; o > 0; o >>= 1) { if (t < o) sh[t] += sh[t + o]; __syncthreads(); }
    float sum = sh[0]; __syncthreads();
    pacc += e / sum;
  }
  if (t < 81) out[(size_t)m * 81 + t] = pacc / 3.0f;
}

// ===========================================================================
extern "C" void kernel_launch(void* const* d_in, const int* in_sizes, int n_in,
                              void* d_out, int out_size, void* d_ws, size_t ws_size,
                              hipStream_t stream)
{
  const float* P2 = (const float*)d_in[0];
  const float* P3 = (const float*)d_in[1];
  const float* P4 = (const float*)d_in[2];
  const float* P5 = (const float*)d_in[3];
  const float* rois = (const float*)d_in[4];
  const float* fc1_w = (const float*)d_in[5];
  const float* fc1_b = (const float*)d_in[6];
  const float* fc2_w = (const float*)d_in[7];
  const float* fc2_b = (const float*)d_in[8];
  const float* cls_w = (const float*)d_in[9];
  const float* cls_b = (const float*)d_in[10];
  const float* reg_w = (const float*)d_in[11];
  const float* reg_b = (const float*)d_in[12];
  float* out = (float*)d_out;

  char* ws = (char*)d_ws;
  size_t off = 0;
  auto alloc = [&](size_t b) -> char* {
    char* p = ws + off;
    off = (off + b + 255) & ~(size_t)255;
    return p;
  };
  unsigned short* w1t_hi = (unsigned short*)alloc(3ull * 1024 * K1 * 2);
  unsigned short* w2t_hi = (unsigned short*)alloc(3ull * 1024 * 1024 * 2);
  unsigned short* w2t_lo = (unsigned short*)alloc(2ull * 1024 * 1024 * 2);
  unsigned short* w3t    = (unsigned short*)alloc(3ull * 128 * 1024 * 2);
  unsigned short* phi    = (unsigned short*)alloc((size_t)MPAD * K1 * 2);
  unsigned short* plo    = (unsigned short*)alloc((size_t)MPAD * K1 * 2);
  unsigned short* h1_hi  = (unsigned short*)alloc(3ull * MPAD * 1024 * 2);
  unsigned short* h1_lo  = (unsigned short*)alloc((size_t)MPAD * 1024 * 2);
  unsigned short* h2_hi  = (unsigned short*)alloc(3ull * MPAD * 1024 * 2);
  float* r1              = (float*)alloc(16384);
  float* r2              = (float*)alloc(16384);
  // w1t_lo LAST: dead after stage 1, so stage-2 partials reuse it + tail.
  const size_t w1lo_bytes = 2ull * 1024 * K1 * 2;
  unsigned short* w1t_lo = (unsigned short*)alloc(w1lo_bytes);

  const size_t SLAB = (size_t)MPAD * 1024 * 4;  // 4 MiB per (s,h) slice
  size_t tail = (ws_size > off) ? (ws_size - off) : 0;

  // stages 0/1 partials in tail; R2-proven sweet spot S=8
  int S01 = (int)(tail / SLAB);
  if (S01 > 8) S01 = 8;
  if (S01 < 1) S01 = 1;
  float* cpart01 = (float*)(ws + off);
  // stage-2 partials alias w1t_lo + tail
  const int S2 = 4;
  float* cpart2 = (float*)w1t_lo;

  const int fc1Steps01 = (392 + S01 - 1) / S01;
  const int fc2Steps01 = (32 + S01 - 1) / S01;

  const long long hs1 = (long long)1024 * K1;
  const long long hs2 = (long long)1024 * 1024;

  dim3 b256(256);

  // --- weight conversion (per call) ---
  hipLaunchKernelGGL(transpose_convert, dim3(K1 / 256, 32, 3), b256, 0, stream,
                     fc1_w, w1t_hi, w1t_lo, K1, 1024, 2);
  hipLaunchKernelGGL(transpose_convert, dim3(4, 32, 3), b256, 0, stream,
                     fc2_w, w2t_hi, w2t_lo, 1024, 1024, 2);
  hipLaunchKernelGGL(transpose_cls, dim3(128, 3), b256, 0, stream, cls_w, w3t);
  hipMemsetAsync(phi + (size_t)NROI * K1, 0, (size_t)(MPAD - NROI) * K1 * 2, stream);
  hipMemsetAsync(plo + (size_t)NROI * K1, 0, (size_t)(MPAD - NROI) * K1 * 2, stream);

  // --- stages 0,1: split-precision path, deltas only ---
  for (int st = 0; st < 2; ++st) {
    const float* rin = (st == 0) ? rois : r1;
    float* rout = (st == 0) ? r1 : r2;
    hipLaunchKernelGGL(roi_align_kernel, dim3(NROI), b256, 0, stream,
                       rin, P2, P3, P4, P5, phi, plo, 1);
    hipLaunchKernelGGL((gemm_bf16<true>), dim3(64, S01, 1), b256, 0, stream,
                       phi, plo, 0LL,
                       w1t_hi + (size_t)st * hs1, w1t_lo + (size_t)st * hs1, 0LL,
                       cpart01, 1024, K1, fc1Steps01);
    hipLaunchKernelGGL(epilogue_kernel, dim3(1024), b256, 0, stream,
                       cpart01, S01, 1, 1024, fc1_b + st * 1024,
                       h1_hi, h1_lo, 4);
    hipLaunchKernelGGL((gemm_bf16<true>), dim3(64, S01, 1), b256, 0, stream,
                       h1_hi, h1_lo, 0LL,
                       w2t_hi + (size_t)st * hs2, w2t_lo + (size_t)st * hs2, 0LL,
                       cpart01, 1024, 1024, fc2Steps01);
    hipLaunchKernelGGL(reg_delta_kernel, dim3(NROI), b256, 0, stream,
                       cpart01, S01, fc2_b + st * 1024,
                       reg_w + (size_t)st * 1024 * 4, reg_b + st * 4,
                       rin, rout);
  }

  // --- stage 2 ---
  hipLaunchKernelGGL(roi_align_kernel, dim3(NROI), b256, 0, stream,
                     r2, P2, P3, P4, P5, phi, plo, 0);
  // fc1 for heads 0,1,2 as ONE fused GEMM: M=1024, N=3072 (w1t_hi is
  // [3][1024][K] = [3072][K] contiguous). 256^2 kernel, split-K by 64-wide
  // K-tiles: 196 tiles, S=5 -> 48*5=240 blocks (~1/CU), 39-40 tiles each.
  {
    const size_t SLAB3 = (size_t)MPAD * 3072 * 4;
    size_t availC2 = ws_size - (size_t)((char*)w1t_lo - ws);
    int S2f = 5;
    while (S2f > 1 && (size_t)S2f * SLAB3 > availC2) --S2f;
    hipLaunchKernelGGL(gemm256_bf16, dim3(48, S2f), dim3(512), 131072, stream,
                       phi, w1t_hi, cpart2, 3072, K1, 196);
    hipLaunchKernelGGL(epilogue_fc1_s2, dim3(3072), b256, 0, stream,
                       cpart2, S2f, fc1_b, h1_hi);
  }
  // fc2: heads batched via blockIdx.z on the 128^2 kernel (K=1024 too small
  // for the 256^2 pipeline to pay off).
  hipLaunchKernelGGL((gemm_bf16<false>), dim3(64, S2, 3), b256, 0, stream,
                     h1_hi, (const unsigned short*)0, hs2,
                     w2t_hi, (const unsigned short*)0, hs2,
                     cpart2, 1024, 1024, (32 + S2 - 1) / S2);
  hipLaunchKernelGGL(epilogue_kernel, dim3(3072), b256, 0, stream,
                     cpart2, S2, 3, 1024, fc2_b,
                     h2_hi, (unsigned short*)0, 0);
  // cls: N=128 (81 real + pad), S=8 -> 192 blocks, 4 steps
  hipLaunchKernelGGL((gemm_bf16<false>), dim3(8, 8, 3), b256, 0, stream,
                     h2_hi, (const unsigned short*)0, hs2,
                     w3t, (const unsigned short*)0, (long long)128 * 1024,
                     cpart2, 128, 1024, 4);
  hipLaunchKernelGGL(softmax_avg_kernel, dim3(NROI), dim3(128), 0, stream,
                     cpart2, 8, cls_b, out);
}

// Round 3
// 789.253 us; speedup vs baseline: 1.0704x; 1.0445x over previous
//
#include <hip/hip_runtime.h>

// ============================================================================
// CascadeRCNN: 3-stage cascade of {pyramid ROI-align -> fc1 -> fc2 -> heads}
//  - Stages 0/1: SPLIT bf16 (hi+lo, 3 MFMA products) fc1/fc2 -> fp32-accurate
//    reg deltas (they feed the discontinuous pyramid-level select).
//  - R7: split fc1 (the two 113-116us top dispatches, MfmaUtil 28%) moved to
//    gemm256s_bf16: BM128xBN256xBK32, 8 waves, 96KB LDS dbuf, 4-phase
//    counted-vmcnt schedule (R6-proven race-free skeleton), 48 MFMA/K-tile.
//    Grid 32 x S01=8 = 256 blocks = 1/CU at proven 32MB partials.
//    Per-acc MFMA chain order identical to old kernel -> same rounding.
//  - Stage 2: fc1 heads fused M=1024xN=3072 on gemm256_bf16 (R6, 256^2 BK64).
//  - fc2/cls stay on the 128^2 kernel (K=1024 too small to matter much).
// ============================================================================

#define BM 128
#define BN 128
#define BK 32
#define K1 12544
#define MPAD 1024
#define NROI 1000

typedef __bf16 bf16_t;
typedef bf16_t bf16x8 __attribute__((ext_vector_type(8)));
typedef float f32x4 __attribute__((ext_vector_type(4)));
typedef float f32x2 __attribute__((ext_vector_type(2)));
typedef unsigned short u16x4 __attribute__((ext_vector_type(4)));
typedef unsigned short u16x2 __attribute__((ext_vector_type(2)));

__device__ __forceinline__ unsigned short f2bf(float x) {
  unsigned u = __float_as_uint(x);
  return (unsigned short)((u + 0x7fffu + ((u >> 16) & 1u)) >> 16);
}
__device__ __forceinline__ float bf2f(unsigned short h) {
  return __uint_as_float(((unsigned)h) << 16);
}

__device__ __forceinline__ void gld_lds16(const void* g, void* l) {
  __builtin_amdgcn_global_load_lds(
      (__attribute__((address_space(1))) void*)g,
      (__attribute__((address_space(3))) void*)l, 16, 0, 0);
}

#define PHASE_SYNC() do { \
  __builtin_amdgcn_s_barrier(); \
  asm volatile("s_waitcnt lgkmcnt(0)" ::: "memory"); \
  __builtin_amdgcn_sched_barrier(0); } while(0)

#define PHASE_END() do { \
  __builtin_amdgcn_s_setprio(0); \
  __builtin_amdgcn_s_barrier(); } while(0)

// ---------------------------------------------------------------------------
// OLD GEMM (128x128x32, 4 waves): kept for split fc2 and stage-2 fc2/cls.
// ---------------------------------------------------------------------------
template <bool SPLIT>
__global__ __launch_bounds__(256, 4)
void gemm_bf16(const unsigned short* __restrict__ Ah,
               const unsigned short* __restrict__ Al,
               long long strideA_head,
               const unsigned short* __restrict__ Bh,
               const unsigned short* __restrict__ Bl,
               long long strideB_head,
               float* __restrict__ Cpart,
               int Nh, int K, int kcSteps)
{
  __shared__ __align__(16) unsigned short sAh[BM * BK];
  __shared__ __align__(16) unsigned short sBh[BN * BK];
  __shared__ __align__(16) unsigned short sAl[SPLIT ? BM * BK : 8];
  __shared__ __align__(16) unsigned short sBl[SPLIT ? BN * BK : 8];

  const int t = threadIdx.x;
  const int ntile = Nh / BN;
  const int bm = blockIdx.x / ntile;
  const int bn = blockIdx.x % ntile;
  const int s = blockIdx.y;
  const int h = blockIdx.z;
  const int H = gridDim.z;

  const unsigned short* Ab = Ah + (size_t)h * strideA_head + (size_t)bm * BM * K;
  const unsigned short* Bb = Bh + (size_t)h * strideB_head + (size_t)bn * BN * K;
  const unsigned short* Alb = SPLIT ? (Al + (size_t)h * strideA_head + (size_t)bm * BM * K) : (const unsigned short*)0;
  const unsigned short* Blb = SPLIT ? (Bl + (size_t)h * strideB_head + (size_t)bn * BN * K) : (const unsigned short*)0;

  int k0 = s * kcSteps * BK;
  int k1 = min(K, k0 + kcSteps * BK);

  const int srow = t >> 2;
  const int gsw = ((t & 3) ^ ((srow >> 1) & 3)) * 8;
  const int lane = t & 63;
  const int wv = t >> 6;
  const int wm = (wv >> 1) * 64;
  const int wn = (wv & 1) * 64;
  const int lr = lane & 15;
  const int q = lane >> 4;
  const int sw = (lr >> 1) & 3;
  const int cA = (q ^ sw) * 8;

  f32x4 acc[4][4];
  const f32x4 z = {0.f, 0.f, 0.f, 0.f};
#pragma unroll
  for (int i = 0; i < 4; ++i)
#pragma unroll
    for (int j = 0; j < 4; ++j) acc[i][j] = z;

  for (int kk = k0; kk < k1; kk += BK) {
#pragma unroll
    for (int j = 0; j < 2; ++j) {
      int row = j * 64 + srow;
      gld_lds16(Ab + (size_t)row * K + kk + gsw, (char*)sAh + j * 4096 + t * 16);
      gld_lds16(Bb + (size_t)row * K + kk + gsw, (char*)sBh + j * 4096 + t * 16);
      if constexpr (SPLIT) {
        gld_lds16(Alb + (size_t)row * K + kk + gsw, (char*)sAl + j * 4096 + t * 16);
        gld_lds16(Blb + (size_t)row * K + kk + gsw, (char*)sBl + j * 4096 + t * 16);
      }
    }
    __syncthreads();

    bf16x8 af[4], bfr[4];
#pragma unroll
    for (int i = 0; i < 4; ++i) af[i] = *(const bf16x8*)&sAh[(wm + i * 16 + lr) * BK + cA];
#pragma unroll
    for (int j = 0; j < 4; ++j) bfr[j] = *(const bf16x8*)&sBh[(wn + j * 16 + lr) * BK + cA];
#pragma unroll
    for (int i = 0; i < 4; ++i)
#pragma unroll
      for (int j = 0; j < 4; ++j)
        acc[i][j] = __builtin_amdgcn_mfma_f32_16x16x32_bf16(af[i], bfr[j], acc[i][j], 0, 0, 0);

    if constexpr (SPLIT) {
      bf16x8 al[4], bl[4];
#pragma unroll
      for (int i = 0; i < 4; ++i) al[i] = *(const bf16x8*)&sAl[(wm + i * 16 + lr) * BK + cA];
#pragma unroll
      for (int j = 0; j < 4; ++j) bl[j] = *(const bf16x8*)&sBl[(wn + j * 16 + lr) * BK + cA];
#pragma unroll
      for (int i = 0; i < 4; ++i)
#pragma unroll
        for (int j = 0; j < 4; ++j) {
          acc[i][j] = __builtin_amdgcn_mfma_f32_16x16x32_bf16(af[i], bl[j], acc[i][j], 0, 0, 0);
          acc[i][j] = __builtin_amdgcn_mfma_f32_16x16x32_bf16(al[i], bfr[j], acc[i][j], 0, 0, 0);
        }
    }
    __syncthreads();
  }

  float* Cb = Cpart + ((size_t)(s * H + h) * MPAD + (size_t)bm * BM) * Nh + (size_t)bn * BN;
#pragma unroll
  for (int i = 0; i < 4; ++i)
#pragma unroll
    for (int j = 0; j < 4; ++j)
#pragma unroll
      for (int r = 0; r < 4; ++r) {
        int m = wm + i * 16 + q * 4 + r;
        int n = wn + j * 16 + lr;
        Cb[(size_t)m * Nh + n] = acc[i][j][r];
      }
}

// ---------------------------------------------------------------------------
// gemm256_bf16 (R6): 256x256 tile, BK=64, 8 waves, 4 phases/K-tile, dbuf,
// counted vmcnt(8). Unsplit; used for stage-2 fused fc1 (N=3072).
// ---------------------------------------------------------------------------
#define DS_A(XB, MH) do { \
    rA[0][0]=lda_f(XB,(MH)*4+0,0); rA[0][1]=lda_f(XB,(MH)*4+0,1); \
    rA[1][0]=lda_f(XB,(MH)*4+1,0); rA[1][1]=lda_f(XB,(MH)*4+1,1); \
    rA[2][0]=lda_f(XB,(MH)*4+2,0); rA[2][1]=lda_f(XB,(MH)*4+2,1); \
    rA[3][0]=lda_f(XB,(MH)*4+3,0); rA[3][1]=lda_f(XB,(MH)*4+3,1); } while(0)

#define DS_B(XB, NH) do { \
    rB[(NH)*2+0][0]=ldb_f(XB,(NH)*2+0,0); rB[(NH)*2+0][1]=ldb_f(XB,(NH)*2+0,1); \
    rB[(NH)*2+1][0]=ldb_f(XB,(NH)*2+1,0); rB[(NH)*2+1][1]=ldb_f(XB,(NH)*2+1,1); } while(0)

#define MFMA_Q(MH, NH) do { \
  _Pragma("unroll") \
  for (int ii = 0; ii < 4; ++ii) { \
    _Pragma("unroll") \
    for (int jj = 0; jj < 2; ++jj) { \
      acc[(MH)*4+ii][(NH)*2+jj] = __builtin_amdgcn_mfma_f32_16x16x32_bf16(rA[ii][0], rB[(NH)*2+jj][0], acc[(MH)*4+ii][(NH)*2+jj], 0, 0, 0); \
      acc[(MH)*4+ii][(NH)*2+jj] = __builtin_amdgcn_mfma_f32_16x16x32_bf16(rA[ii][1], rB[(NH)*2+jj][1], acc[(MH)*4+ii][(NH)*2+jj], 0, 0, 0); \
    } } } while(0)

__global__ __launch_bounds__(512, 2)
void gemm256_bf16(const unsigned short* __restrict__ A,
                  const unsigned short* __restrict__ B,
                  float* __restrict__ Cpart,
                  int Ntot, int K, int tilesTotal)
{
  extern __shared__ char lds[];
  const int t = threadIdx.x;
  const int ntile = Ntot >> 8;
  const int bm = blockIdx.x / ntile;
  const int bn = blockIdx.x % ntile;
  const int s = blockIdx.y;
  const int S = gridDim.y;
  const int qp = tilesTotal / S, rp = tilesTotal % S;
  const int t0 = s * qp + (s < rp ? s : rp);
  const int np = qp + (s < rp ? 1 : 0);

  const unsigned short* Ab = A + (size_t)bm * 256 * K;
  const unsigned short* Bb = B + (size_t)bn * 256 * K;

  const int srow = t >> 3;
  const int sgrp = ((t & 7) ^ (srow & 7)) << 3;

  const int lane = t & 63;
  const int wv = t >> 6;
  const int wm = (wv >> 2) << 7;
  const int wn = (wv & 3) << 6;
  const int lr = lane & 15;
  const int q = lane >> 4;

  f32x4 acc[8][4];
  const f32x4 z = {0.f, 0.f, 0.f, 0.f};
#pragma unroll
  for (int i = 0; i < 8; ++i)
#pragma unroll
    for (int j = 0; j < 4; ++j) acc[i][j] = z;

  bf16x8 rA[4][2], rB[4][2];

  auto stage_tile = [&](int xbuf, int kt) {
    const size_t col = ((size_t)(t0 + kt) << 6) + sgrp;
#pragma unroll
    for (int u = 0; u < 4; ++u) {
      const unsigned short* src = (u < 2) ? Ab : Bb;
      const int rbase = ((u & 1) << 7) + srow;
      char* dst = lds + xbuf * 65536 + ((u & 2) << 14) + ((u & 1) << 14) + t * 16;
      gld_lds16(src + (size_t)rbase * K + col, dst);
      gld_lds16(src + (size_t)(rbase + 64) * K + col, dst + 8192);
    }
  };

  auto lda_f = [&](int xbuf, int i, int ks) -> bf16x8 {
    const int row = wm + (i << 4) + lr;
    const int pg = (ks * 4 + q) ^ (row & 7);
    return *(const bf16x8*)(lds + xbuf * 65536 + row * 128 + pg * 16);
  };
  auto ldb_f = [&](int xbuf, int j, int ks) -> bf16x8 {
    const int row = wn + (j << 4) + lr;
    const int pg = (ks * 4 + q) ^ (row & 7);
    return *(const bf16x8*)(lds + xbuf * 65536 + 32768 + row * 128 + pg * 16);
  };

  stage_tile(0, 0);
  if (np > 1) {
    stage_tile(1, 1);
    asm volatile("s_waitcnt vmcnt(8)" ::: "memory");
  } else {
    asm volatile("s_waitcnt vmcnt(0)" ::: "memory");
  }
  __builtin_amdgcn_s_barrier();

  for (int i = 0; i < np; ++i) {
    const int buf = i & 1;
    const bool st = (i + 2 < np);
    DS_A(buf, 0);
    DS_B(buf, 0);
    PHASE_SYNC();
    __builtin_amdgcn_s_setprio(1);
    MFMA_Q(0, 0);
    PHASE_END();
    DS_B(buf, 1);
    PHASE_SYNC();
    __builtin_amdgcn_s_setprio(1);
    MFMA_Q(0, 1);
    PHASE_END();
    DS_A(buf, 1);
    PHASE_SYNC();
    __builtin_amdgcn_s_setprio(1);
    MFMA_Q(1, 0);
    PHASE_END();
    if (st) {
      stage_tile(buf, i + 2);
      asm volatile("s_waitcnt vmcnt(8)" ::: "memory");
    } else {
      asm volatile("s_waitcnt vmcnt(0)" ::: "memory");
    }
    __builtin_amdgcn_s_barrier();
    __builtin_amdgcn_sched_barrier(0);
    __builtin_amdgcn_s_setprio(1);
    MFMA_Q(1, 1);
    __builtin_amdgcn_s_setprio(0);
  }

  float* Cb = Cpart + (size_t)s * MPAD * Ntot +
              (size_t)(bm * 256 + wm) * Ntot + bn * 256 + wn;
#pragma unroll
  for (int i = 0; i < 8; ++i)
#pragma unroll
    for (int j = 0; j < 4; ++j)
#pragma unroll
      for (int r = 0; r < 4; ++r)
        Cb[(size_t)(i * 16 + q * 4 + r) * Ntot + j * 16 + lr] = acc[i][j][r];
}

// ---------------------------------------------------------------------------
// NEW (R7) gemm256s_bf16: SPLIT GEMM on the R6 pipeline skeleton.
// BM=128 x BN=256 x BK=32, 8 waves (2Mx4N), each wave 64x64 out.
// LDS buf (49152B): Ah@0 (8K), Al@8192, Bh@16384 (16K), Bl@32768; dbuf=96KB.
// Per K-tile: 16 ds_read_b128, 48 MFMA (3 products), 6 gld_lds16.
// Swizzle: physical group pg holds logical group pg ^ (row&3) (64B rows,
// 4x16B groups) -> perfectly bank-balanced wave64 b128 reads.
// Schedule (R6-proven): reads of buf in P1-P3; P4 stages tile i+2 into buf
// AFTER P3's end-barrier (WAR-safe); counted vmcnt(6); barrier; Q(1,1).
// Per-acc chain order per 32-K-step: +AhBh, +AhBl, +AlBh (== old kernel).
// ---------------------------------------------------------------------------
#define S_DS_A(XB, MH) do { \
    rAh[0]=s_lda(XB,0,(MH)*2+0); rAh[1]=s_lda(XB,0,(MH)*2+1); \
    rAl[0]=s_lda(XB,1,(MH)*2+0); rAl[1]=s_lda(XB,1,(MH)*2+1); } while(0)

#define S_DS_B(XB, NH) do { \
    rBh[(NH)*2+0]=s_ldb(XB,0,(NH)*2+0); rBh[(NH)*2+1]=s_ldb(XB,0,(NH)*2+1); \
    rBl[(NH)*2+0]=s_ldb(XB,1,(NH)*2+0); rBl[(NH)*2+1]=s_ldb(XB,1,(NH)*2+1); } while(0)

#define S_MFMA_Q(MH, NH) do { \
  _Pragma("unroll") \
  for (int ii = 0; ii < 2; ++ii) { \
    _Pragma("unroll") \
    for (int jj = 0; jj < 2; ++jj) { \
      f32x4* a = &acc[(MH)*2+ii][(NH)*2+jj]; \
      *a = __builtin_amdgcn_mfma_f32_16x16x32_bf16(rAh[ii], rBh[(NH)*2+jj], *a, 0, 0, 0); \
      *a = __builtin_amdgcn_mfma_f32_16x16x32_bf16(rAh[ii], rBl[(NH)*2+jj], *a, 0, 0, 0); \
      *a = __builtin_amdgcn_mfma_f32_16x16x32_bf16(rAl[ii], rBh[(NH)*2+jj], *a, 0, 0, 0); \
    } } } while(0)

__global__ __launch_bounds__(512, 2)
void gemm256s_bf16(const unsigned short* __restrict__ Ah,
                   const unsigned short* __restrict__ Al,
                   const unsigned short* __restrict__ Bh,
                   const unsigned short* __restrict__ Bl,
                   float* __restrict__ Cpart,
                   int Ntot, int K, int tilesTotal)
{
  extern __shared__ char lds[];
  const int t = threadIdx.x;
  const int ntile = Ntot >> 8;                 // N-tiles of 256
  const int bm = blockIdx.x / ntile;           // M-tiles of 128
  const int bn = blockIdx.x % ntile;
  const int s = blockIdx.y;
  const int S = gridDim.y;
  const int qp = tilesTotal / S, rp = tilesTotal % S;
  const int t0 = s * qp + (s < rp ? s : rp);
  const int np = qp + (s < rp ? 1 : 0);

  const unsigned short* Ahb = Ah + (size_t)bm * 128 * K;
  const unsigned short* Alb = Al + (size_t)bm * 128 * K;
  const unsigned short* Bhb = Bh + (size_t)bn * 256 * K;
  const unsigned short* Blb = Bl + (size_t)bn * 256 * K;

  // staging: 64B rows, 4 threads/row; physical slot (row, pg=t&3) holds
  // logical group (t&3)^(row&3) -> pre-swizzled global source column.
  const int srow = t >> 2;                       // 0..127
  const int sgrp = ((t & 3) ^ (srow & 3)) << 3;  // source col group (elems)

  const int lane = t & 63;
  const int wv = t >> 6;
  const int wm = (wv >> 2) << 6;   // 0 / 64
  const int wn = (wv & 3) << 6;    // 0 / 64 / 128 / 192
  const int lr = lane & 15;
  const int q = lane >> 4;

  f32x4 acc[4][4];
  const f32x4 z = {0.f, 0.f, 0.f, 0.f};
#pragma unroll
  for (int i = 0; i < 4; ++i)
#pragma unroll
    for (int j = 0; j < 4; ++j) acc[i][j] = z;

  bf16x8 rAh[2], rAl[2], rBh[4], rBl[4];

  // 6 gld_lds16 per thread per K-tile
  auto stage_tile = [&](int xbuf, int kt) {
    const size_t col = ((size_t)(t0 + kt) << 5) + sgrp;
    char* base = lds + xbuf * 49152;
    gld_lds16(Ahb + (size_t)srow * K + col, base + t * 16);
    gld_lds16(Alb + (size_t)srow * K + col, base + 8192 + t * 16);
    gld_lds16(Bhb + (size_t)srow * K + col, base + 16384 + t * 16);
    gld_lds16(Bhb + (size_t)(srow + 128) * K + col, base + 16384 + 8192 + t * 16);
    gld_lds16(Blb + (size_t)srow * K + col, base + 32768 + t * 16);
    gld_lds16(Blb + (size_t)(srow + 128) * K + col, base + 32768 + 8192 + t * 16);
  };

  auto s_lda = [&](int xbuf, int pl, int i) -> bf16x8 {
    const int row = wm + (i << 4) + lr;          // 0..127
    const int pg = q ^ (row & 3);
    return *(const bf16x8*)(lds + xbuf * 49152 + pl * 8192 + row * 64 + pg * 16);
  };
  auto s_ldb = [&](int xbuf, int pl, int j) -> bf16x8 {
    const int row = wn + (j << 4) + lr;          // 0..255
    const int pg = q ^ (row & 3);
    return *(const bf16x8*)(lds + xbuf * 49152 + 16384 + pl * 16384 + row * 64 + pg * 16);
  };

  // prologue: tile0 -> buf0, tile1 -> buf1; counted wait for tile0
  stage_tile(0, 0);
  if (np > 1) {
    stage_tile(1, 1);
    asm volatile("s_waitcnt vmcnt(6)" ::: "memory");
  } else {
    asm volatile("s_waitcnt vmcnt(0)" ::: "memory");
  }
  __builtin_amdgcn_s_barrier();

  for (int i = 0; i < np; ++i) {
    const int buf = i & 1;
    const bool st = (i + 2 < np);
    // P1: A half0 (4) + B group0 (4) ds_reads; Q(0,0) 12 MFMA
    S_DS_A(buf, 0);
    S_DS_B(buf, 0);
    PHASE_SYNC();
    __builtin_amdgcn_s_setprio(1);
    S_MFMA_Q(0, 0);
    PHASE_END();
    // P2: B group1 (4); Q(0,1)
    S_DS_B(buf, 1);
    PHASE_SYNC();
    __builtin_amdgcn_s_setprio(1);
    S_MFMA_Q(0, 1);
    PHASE_END();
    // P3: A half1 (4); Q(1,0)
    S_DS_A(buf, 1);
    PHASE_SYNC();
    __builtin_amdgcn_s_setprio(1);
    S_MFMA_Q(1, 0);
    PHASE_END();
    // P4: stage tile i+2 (WAR-safe: all reads of buf done at P3 END barrier),
    //     counted vmcnt(6) = tile i+1 landed, i+2 in flight; barrier; Q(1,1).
    if (st) {
      stage_tile(buf, i + 2);
      asm volatile("s_waitcnt vmcnt(6)" ::: "memory");
    } else {
      asm volatile("s_waitcnt vmcnt(0)" ::: "memory");
    }
    __builtin_amdgcn_s_barrier();
    __builtin_amdgcn_sched_barrier(0);
    __builtin_amdgcn_s_setprio(1);
    S_MFMA_Q(1, 1);
    __builtin_amdgcn_s_setprio(0);
  }

  float* Cb = Cpart + (size_t)s * MPAD * Ntot +
              (size_t)(bm * 128 + wm) * Ntot + bn * 256 + wn;
#pragma unroll
  for (int i = 0; i < 4; ++i)
#pragma unroll
    for (int j = 0; j < 4; ++j)
#pragma unroll
      for (int r = 0; r < 4; ++r)
        Cb[(size_t)(i * 16 + q * 4 + r) * Ntot + j * 16 + lr] = acc[i][j][r];
}

// ---------------------------------------------------------------------------
// Epilogue (x4 vectorized): v = relu(sum_s partial + bias), emit bf16 hi[,lo].
// ---------------------------------------------------------------------------
__global__ __launch_bounds__(256)
void epilogue_kernel(const float* __restrict__ Cpart, int S, int H, int Nh,
                     const float* __restrict__ bias,
                     unsigned short* __restrict__ ohi,
                     unsigned short* __restrict__ olo, int flags)
{
  size_t total = (size_t)H * MPAD * Nh;
  size_t idx = ((size_t)blockIdx.x * 256 + threadIdx.x) * 4;
  if (idx >= total) return;
  int n = (int)(idx % Nh);
  int h = (int)(idx / ((size_t)MPAD * Nh));
  f32x4 v = *(const f32x4*)&bias[(size_t)h * Nh + n];
  for (int s = 0; s < S; ++s) v += *(const f32x4*)&Cpart[(size_t)s * total + idx];
  u16x4 hi, lo;
#pragma unroll
  for (int j = 0; j < 4; ++j) {
    float x = fmaxf(v[j], 0.f);
    hi[j] = f2bf(x);
    lo[j] = f2bf(x - bf2f(hi[j]));
  }
  *(u16x4*)&ohi[idx] = hi;
  if (flags & 4) *(u16x4*)&olo[idx] = lo;
}

// Epilogue for stage-2 fused fc1 (N=3072): partials [s][1024][3072],
// de-interleave into h1_hi[h][1024][1024]. bias = fc1_b (3x1024 contiguous).
__global__ __launch_bounds__(256)
void epilogue_fc1_s2(const float* __restrict__ Cpart, int S,
                     const float* __restrict__ bias,
                     unsigned short* __restrict__ ohi)
{
  const size_t total = (size_t)MPAD * 3072;
  size_t idx = ((size_t)blockIdx.x * 256 + threadIdx.x) * 4;
  if (idx >= total) return;
  int n = (int)(idx % 3072);
  int m = (int)(idx / 3072);
  f32x4 v = *(const f32x4*)&bias[n];
  for (int s = 0; s < S; ++s) v += *(const f32x4*)&Cpart[(size_t)s * total + idx];
  u16x4 hi;
#pragma unroll
  for (int j = 0; j < 4; ++j) hi[j] = f2bf(fmaxf(v[j], 0.f));
  int h = n >> 10;
  *(u16x4*)&ohi[((size_t)h * MPAD + m) * 1024 + (n & 1023)] = hi;
}

// ---------------------------------------------------------------------------
// Transpose + fp32->bf16 hi/lo: W[H][K][N] -> T[H][N][K].
// ---------------------------------------------------------------------------
__global__ __launch_bounds__(256)
void transpose_convert(const float* __restrict__ W,
                       unsigned short* __restrict__ Thi,
                       unsigned short* __restrict__ Tlo,
                       int K, int N, int loHeads)
{
  __shared__ float tile[32][260];
  int kb = blockIdx.x * 256;
  int nb = blockIdx.y * 32;
  int h = blockIdx.z;
  const float* Wb = W + (size_t)h * K * N + (size_t)kb * N + nb;
  int tn = threadIdx.x & 31;
  int tk = threadIdx.x >> 5;
#pragma unroll
  for (int i = 0; i < 32; ++i) {
    int k = tk + i * 8;
    tile[tn][k] = Wb[(size_t)k * N + tn];
  }
  __syncthreads();
  bool wlo = h < loHeads;
  int l = threadIdx.x & 63;
  int ng = threadIdx.x >> 6;
  size_t ob = (size_t)h * N * K + (size_t)nb * K + kb;
#pragma unroll
  for (int i = 0; i < 8; ++i) {
    int n = ng + i * 4;
    f32x4 v = *(const f32x4*)&tile[n][4 * l];
    u16x4 hi;
#pragma unroll
    for (int j = 0; j < 4; ++j) hi[j] = f2bf(v[j]);
    *(u16x4*)&Thi[ob + (size_t)n * K + 4 * l] = hi;
    if (wlo) {
      u16x4 lo;
#pragma unroll
      for (int j = 0; j < 4; ++j) lo[j] = f2bf(v[j] - bf2f(hi[j]));
      *(u16x4*)&Tlo[ob + (size_t)n * K + 4 * l] = lo;
    }
  }
}

// cls_w (3,1024,81) -> w3t (3,128,1024) bf16, rows 81..127 zero. grid (128,3).
__global__ void transpose_cls(const float* __restrict__ W, unsigned short* __restrict__ T)
{
  int n = blockIdx.x, h = blockIdx.y, t = threadIdx.x;
  size_t ob = ((size_t)h * 128 + n) * 1024;
  if (n < 81) {
    for (int k = t; k < 1024; k += 256)
      T[ob + k] = f2bf(W[((size_t)h * 1024 + k) * 81 + n]);
  } else {
    for (int k = t; k < 1024; k += 256) T[ob + k] = 0;
  }
}

// ---------------------------------------------------------------------------
// Pyramid ROI-align: one block per roi; 64 channel-quads x 4 position groups.
// ---------------------------------------------------------------------------
__global__ void roi_align_kernel(const float* __restrict__ rois,
                                 const float* __restrict__ P2, const float* __restrict__ P3,
                                 const float* __restrict__ P4, const float* __restrict__ P5,
                                 unsigned short* __restrict__ phi,
                                 unsigned short* __restrict__ plo, int writeLo)
{
  int m = blockIdx.x;
  int t = threadIdx.x;
  int c = (t & 63) * 4;
  int pg = t >> 6;  // 0..3
  const float* rp = rois + m * 4;
  float y1 = rp[0], x1 = rp[1], y2 = rp[2], x2 = rp[3];
  float hh = y2 - y1, ww = x2 - x1;
  float a = sqrtf(fmaxf(hh * ww, 1e-6f)) / 224.0f;
  float lvl = floorf(4.0f + log2f(a));
  lvl = fminf(fmaxf(lvl, 2.0f), 5.0f);
  int i = (int)lvl - 2;
  const float* f = (i == 0) ? P2 : (i == 1) ? P3 : (i == 2) ? P4 : P5;
  int H = 256 >> i;
  float stride = (float)(4 << i);
  float sy1 = y1 / stride, sx1 = x1 / stride;
  float dy = y2 / stride - sy1, dx = x2 / stride - sx1;
  size_t base = (size_t)m * K1 + c;
  for (int p = pg; p < 49; p += 4) {
    int py = p / 7, px = p % 7;
    float ys = sy1 + ((py + 0.5f) / 7.0f) * dy;
    float xs = sx1 + ((px + 0.5f) / 7.0f) * dx;
    float y0f = fminf(fmaxf(floorf(ys), 0.0f), (float)(H - 1));
    float x0f = fminf(fmaxf(floorf(xs), 0.0f), (float)(H - 1));
    int y0 = (int)y0f, x0 = (int)x0f;
    int y1i = min(y0 + 1, H - 1), x1i = min(x0 + 1, H - 1);
    float wy = fminf(fmaxf(ys - y0f, 0.0f), 1.0f);
    float wx = fminf(fmaxf(xs - x0f, 0.0f), 1.0f);
    f32x4 v00 = *(const f32x4*)(f + ((size_t)y0 * H + x0) * 256 + c);
    f32x4 v01 = *(const f32x4*)(f + ((size_t)y0 * H + x1i) * 256 + c);
    f32x4 v10 = *(const f32x4*)(f + ((size_t)y1i * H + x0) * 256 + c);
    f32x4 v11 = *(const f32x4*)(f + ((size_t)y1i * H + x1i) * 256 + c);
    float w00 = (1.f - wy) * (1.f - wx), w01 = (1.f - wy) * wx;
    float w10 = wy * (1.f - wx), w11 = wy * wx;
    f32x4 v = v00 * w00 + v01 * w01 + v10 * w10 + v11 * w11;
    u16x4 hi;
#pragma unroll
    for (int j = 0; j < 4; ++j) hi[j] = f2bf(v[j]);
    *(u16x4*)&phi[base + p * 256] = hi;
    if (writeLo) {
      u16x4 lo;
#pragma unroll
      for (int j = 0; j < 4; ++j) lo[j] = f2bf(v[j] - bf2f(hi[j]));
      *(u16x2*)&plo[base + p * 256] = *(u16x2*)&lo;
      *(u16x2*)&plo[base + p * 256 + 2] = *((u16x2*)&lo + 1);
    }
  }
}

// ---------------------------------------------------------------------------
// FUSED fc2-epilogue + reg head + delta2bbox (stages 0/1).
// ---------------------------------------------------------------------------
__global__ void reg_delta_kernel(const float* __restrict__ Cpart, int S,
                                 const float* __restrict__ fb,
                                 const float* __restrict__ rw, const float* __restrict__ rb,
                                 const float* __restrict__ rin, float* __restrict__ rout)
{
  int m = blockIdx.x, t = threadIdx.x;
  float s0 = 0, s1 = 0, s2 = 0, s3 = 0;
  for (int n = t; n < 1024; n += 256) {
    float v = fb[n];
    for (int s = 0; s < S; ++s) v += Cpart[((size_t)s * 1024 + m) * 1024 + n];
    v = fmaxf(v, 0.f);
    const float* w = rw + (size_t)n * 4;
    s0 += v * w[0]; s1 += v * w[1]; s2 += v * w[2]; s3 += v * w[3];
  }
#pragma unroll
  for (int o = 32; o > 0; o >>= 1) {
    s0 += __shfl_xor(s0, o, 64);
    s1 += __shfl_xor(s1, o, 64);
    s2 += __shfl_xor(s2, o, 64);
    s3 += __shfl_xor(s3, o, 64);
  }
  __shared__ float part[4][4];
  int w = t >> 6;
  if ((t & 63) == 0) { part[w][0] = s0; part[w][1] = s1; part[w][2] = s2; part[w][3] = s3; }
  __syncthreads();
  if (t == 0) {
    float d0 = (part[0][0] + part[1][0] + part[2][0] + part[3][0] + rb[0]) * 0.1f;
    float d1 = (part[0][1] + part[1][1] + part[2][1] + part[3][1] + rb[1]) * 0.1f;
    float d2 = (part[0][2] + part[1][2] + part[2][2] + part[3][2] + rb[2]) * 0.2f;
    float d3 = (part[0][3] + part[1][3] + part[2][3] + part[3][3] + rb[3]) * 0.2f;
    const float* r = rin + m * 4;
    float y1 = r[0], x1 = r[1], y2 = r[2], x2 = r[3];
    float h = y2 - y1, wd = x2 - x1;
    float cy = y1 + 0.5f * h + d0 * h;
    float cx = x1 + 0.5f * wd + d1 * wd;
    float nh = h * expf(d2);
    float nw = wd * expf(d3);
    float* ro = rout + m * 4;
    ro[0] = fminf(fmaxf(cy - 0.5f * nh, 0.f), 1024.f);
    ro[1] = fminf(fmaxf(cx - 0.5f * nw, 0.f), 1024.f);
    ro[2] = fminf(fmaxf(cy + 0.5f * nh, 0.f), 1024.f);
    ro[3] = fminf(fmaxf(cx + 0.5f * nw, 0.f), 1024.f);
  }
}

// ---------------------------------------------------------------------------
// FUSED cls-epilogue + softmax + 3-head average.
// ---------------------------------------------------------------------------
__global__ void softmax_avg_kernel(const float* __restrict__ Cpart, int S,
                                   const float* __restrict__ cls_b,
                                   float* __restrict__ out)
{
  int m = blockIdx.x, t = threadIdx.x;
  __shared__ float sh[128];
  float pacc = 0.0f;
  for (int h = 0; h < 3; ++h) {
    float x = -3.0e38f;
    if (t < 81) {
      x = cls_b[h * 81 + t];
      for (int s = 0; s < S; ++s)
        x += Cpart[((size_t)(s * 3 + h) * 1024 + m) * 128 + t];
    }
    sh[t] = x; __syncthreads();
    for (int o = 64; o > 0; o >>= 1) { if (t < o) sh[t] = fmaxf(sh[t], sh[t + o]); __syncthreads(); }
    float mx = sh[0]; __syncthreads();
    float e = (t < 81) ? expf(x - mx) : 0.0f;
    sh[t] = e; __syncthreads();
    for (int o = 64; o > 0; o >>= 1) { if (t < o) sh[t] += sh[t + o]; __syncthreads(); }
    float sum = sh[0]; __syncthreads();
    pacc += e / sum;
  }
  if (t < 81) out[(size_t)m * 81 + t] = pacc / 3.0f;
}

// ===========================================================================
extern "C" void kernel_launch(void* const* d_in, const int* in_sizes, int n_in,
                              void* d_out, int out_size, void* d_ws, size_t ws_size,
                              hipStream_t stream)
{
  const float* P2 = (const float*)d_in[0];
  const float* P3 = (const float*)d_in[1];
  const float* P4 = (const float*)d_in[2];
  const float* P5 = (const float*)d_in[3];
  const float* rois = (const float*)d_in[4];
  const float* fc1_w = (const float*)d_in[5];
  const float* fc1_b = (const float*)d_in[6];
  const float* fc2_w = (const float*)d_in[7];
  const float* fc2_b = (const float*)d_in[8];
  const float* cls_w = (const float*)d_in[9];
  const float* cls_b = (const float*)d_in[10];
  const float* reg_w = (const float*)d_in[11];
  const float* reg_b = (const float*)d_in[12];
  float* out = (float*)d_out;

  char* ws = (char*)d_ws;
  size_t off = 0;
  auto alloc = [&](size_t b) -> char* {
    char* p = ws + off;
    off = (off + b + 255) & ~(size_t)255;
    return p;
  };
  unsigned short* w1t_hi = (unsigned short*)alloc(3ull * 1024 * K1 * 2);
  unsigned short* w2t_hi = (unsigned short*)alloc(3ull * 1024 * 1024 * 2);
  unsigned short* w2t_lo = (unsigned short*)alloc(2ull * 1024 * 1024 * 2);
  unsigned short* w3t    = (unsigned short*)alloc(3ull * 128 * 1024 * 2);
  unsigned short* phi    = (unsigned short*)alloc((size_t)MPAD * K1 * 2);
  unsigned short* plo    = (unsigned short*)alloc((size_t)MPAD * K1 * 2);
  unsigned short* h1_hi  = (unsigned short*)alloc(3ull * MPAD * 1024 * 2);
  unsigned short* h1_lo  = (unsigned short*)alloc((size_t)MPAD * 1024 * 2);
  unsigned short* h2_hi  = (unsigned short*)alloc(3ull * MPAD * 1024 * 2);
  float* r1              = (float*)alloc(16384);
  float* r2              = (float*)alloc(16384);
  // w1t_lo LAST: dead after stage 1, so stage-2 partials reuse it + tail.
  const size_t w1lo_bytes = 2ull * 1024 * K1 * 2;
  unsigned short* w1t_lo = (unsigned short*)alloc(w1lo_bytes);

  const size_t SLAB = (size_t)MPAD * 1024 * 4;  // 4 MiB per (s,h) slice
  size_t tail = (ws_size > off) ? (ws_size - off) : 0;

  // stages 0/1 partials in tail; R2-proven sweet spot S=8
  int S01 = (int)(tail / SLAB);
  if (S01 > 8) S01 = 8;
  if (S01 < 1) S01 = 1;
  float* cpart01 = (float*)(ws + off);
  // stage-2 partials alias w1t_lo + tail
  const int S2 = 4;
  float* cpart2 = (float*)w1t_lo;

  const int fc2Steps01 = (32 + S01 - 1) / S01;

  const long long hs1 = (long long)1024 * K1;
  const long long hs2 = (long long)1024 * 1024;

  dim3 b256(256);

  // --- weight conversion (per call) ---
  hipLaunchKernelGGL(transpose_convert, dim3(K1 / 256, 32, 3), b256, 0, stream,
                     fc1_w, w1t_hi, w1t_lo, K1, 1024, 2);
  hipLaunchKernelGGL(transpose_convert, dim3(4, 32, 3), b256, 0, stream,
                     fc2_w, w2t_hi, w2t_lo, 1024, 1024, 2);
  hipLaunchKernelGGL(transpose_cls, dim3(128, 3), b256, 0, stream, cls_w, w3t);
  hipMemsetAsync(phi + (size_t)NROI * K1, 0, (size_t)(MPAD - NROI) * K1 * 2, stream);
  hipMemsetAsync(plo + (size_t)NROI * K1, 0, (size_t)(MPAD - NROI) * K1 * 2, stream);

  // --- stages 0,1: split-precision path, deltas only ---
  for (int st = 0; st < 2; ++st) {
    const float* rin = (st == 0) ? rois : r1;
    float* rout = (st == 0) ? r1 : r2;
    hipLaunchKernelGGL(roi_align_kernel, dim3(NROI), b256, 0, stream,
                       rin, P2, P3, P4, P5, phi, plo, 1);
    // SPLIT fc1 on the new 128x256xBK32 4-phase kernel:
    // grid 32 x S01(=8) = 256 blocks = 1/CU; 392 K-tiles of 32.
    hipLaunchKernelGGL(gemm256s_bf16, dim3(32, S01), dim3(512), 98304, stream,
                       phi, plo,
                       w1t_hi + (size_t)st * hs1, w1t_lo + (size_t)st * hs1,
                       cpart01, 1024, K1, 392);
    hipLaunchKernelGGL(epilogue_kernel, dim3(1024), b256, 0, stream,
                       cpart01, S01, 1, 1024, fc1_b + st * 1024,
                       h1_hi, h1_lo, 4);
    hipLaunchKernelGGL((gemm_bf16<true>), dim3(64, S01, 1), b256, 0, stream,
                       h1_hi, h1_lo, 0LL,
                       w2t_hi + (size_t)st * hs2, w2t_lo + (size_t)st * hs2, 0LL,
                       cpart01, 1024, 1024, fc2Steps01);
    hipLaunchKernelGGL(reg_delta_kernel, dim3(NROI), b256, 0, stream,
                       cpart01, S01, fc2_b + st * 1024,
                       reg_w + (size_t)st * 1024 * 4, reg_b + st * 4,
                       rin, rout);
  }

  // --- stage 2 ---
  hipLaunchKernelGGL(roi_align_kernel, dim3(NROI), b256, 0, stream,
                     r2, P2, P3, P4, P5, phi, plo, 0);
  // fc1 for heads 0,1,2 as ONE fused GEMM: M=1024, N=3072 on gemm256_bf16.
  {
    const size_t SLAB3 = (size_t)MPAD * 3072 * 4;
    size_t availC2 = ws_size - (size_t)((char*)w1t_lo - ws);
    int S2f = 5;
    while (S2f > 1 && (size_t)S2f * SLAB3 > availC2) --S2f;
    hipLaunchKernelGGL(gemm256_bf16, dim3(48, S2f), dim3(512), 131072, stream,
                       phi, w1t_hi, cpart2, 3072, K1, 196);
    hipLaunchKernelGGL(epilogue_fc1_s2, dim3(3072), b256, 0, stream,
                       cpart2, S2f, fc1_b, h1_hi);
  }
  // fc2: heads batched via blockIdx.z on the 128^2 kernel.
  hipLaunchKernelGGL((gemm_bf16<false>), dim3(64, S2, 3), b256, 0, stream,
                     h1_hi, (const unsigned short*)0, hs2,
                     w2t_hi, (const unsigned short*)0, hs2,
                     cpart2, 1024, 1024, (32 + S2 - 1) / S2);
  hipLaunchKernelGGL(epilogue_kernel, dim3(3072), b256, 0, stream,
                     cpart2, S2, 3, 1024, fc2_b,
                     h2_hi, (unsigned short*)0, 0);
  // cls: N=128 (81 real + pad), S=8 -> 192 blocks, 4 steps
  hipLaunchKernelGGL((gemm_bf16<false>), dim3(8, 8, 3), b256, 0, stream,
                     h2_hi, (const unsigned short*)0, hs2,
                     w3t, (const unsigned short*)0, (long long)128 * 1024,
                     cpart2, 128, 1024, 4);
  hipLaunchKernelGGL(softmax_avg_kernel, dim3(NROI), dim3(128), 0, stream,
                     cpart2, 8, cls_b, out);
}

// Round 4
// 786.714 us; speedup vs baseline: 1.0738x; 1.0032x over previous
//
#include <hip/hip_runtime.h>

// ============================================================================
// CascadeRCNN: 3-stage cascade of {pyramid ROI-align -> fc1 -> fc2 -> heads}
//  - Stages 0/1: SPLIT bf16 (hi+lo, 3 MFMA products) fc1/fc2 -> fp32-accurate
//    reg deltas (they feed the discontinuous pyramid-level select).
//  - R8: fix gemm256s LDS swizzle. R7 used pg = q^(row&3), which with 64B
//    rows (start bank = row*16 mod 32 alternating 0/16) left each 16-lane
//    group on only 4/8 bank-groups -> 6.4M conflict cycles. Proven formula
//    (same as old 0-conflict kernel): pg = q ^ ((row>>1)&3), applied on BOTH
//    staging source and read side (same involution).
//  - R7: split fc1 on gemm256s_bf16: BM128xBN256xBK32, 8 waves, 96KB LDS
//    dbuf, 4-phase counted-vmcnt schedule, 48 MFMA/K-tile, 256 blocks=1/CU.
//  - Stage 2: fc1 heads fused M=1024xN=3072 on gemm256_bf16 (R6, 256^2 BK64).
//  - fc2/cls stay on the 128^2 kernel.
// ============================================================================

#define BM 128
#define BN 128
#define BK 32
#define K1 12544
#define MPAD 1024
#define NROI 1000

typedef __bf16 bf16_t;
typedef bf16_t bf16x8 __attribute__((ext_vector_type(8)));
typedef float f32x4 __attribute__((ext_vector_type(4)));
typedef float f32x2 __attribute__((ext_vector_type(2)));
typedef unsigned short u16x4 __attribute__((ext_vector_type(4)));
typedef unsigned short u16x2 __attribute__((ext_vector_type(2)));

__device__ __forceinline__ unsigned short f2bf(float x) {
  unsigned u = __float_as_uint(x);
  return (unsigned short)((u + 0x7fffu + ((u >> 16) & 1u)) >> 16);
}
__device__ __forceinline__ float bf2f(unsigned short h) {
  return __uint_as_float(((unsigned)h) << 16);
}

__device__ __forceinline__ void gld_lds16(const void* g, void* l) {
  __builtin_amdgcn_global_load_lds(
      (__attribute__((address_space(1))) void*)g,
      (__attribute__((address_space(3))) void*)l, 16, 0, 0);
}

#define PHASE_SYNC() do { \
  __builtin_amdgcn_s_barrier(); \
  asm volatile("s_waitcnt lgkmcnt(0)" ::: "memory"); \
  __builtin_amdgcn_sched_barrier(0); } while(0)

#define PHASE_END() do { \
  __builtin_amdgcn_s_setprio(0); \
  __builtin_amdgcn_s_barrier(); } while(0)

// ---------------------------------------------------------------------------
// OLD GEMM (128x128x32, 4 waves): kept for split fc2 and stage-2 fc2/cls.
// ---------------------------------------------------------------------------
template <bool SPLIT>
__global__ __launch_bounds__(256, 4)
void gemm_bf16(const unsigned short* __restrict__ Ah,
               const unsigned short* __restrict__ Al,
               long long strideA_head,
               const unsigned short* __restrict__ Bh,
               const unsigned short* __restrict__ Bl,
               long long strideB_head,
               float* __restrict__ Cpart,
               int Nh, int K, int kcSteps)
{
  __shared__ __align__(16) unsigned short sAh[BM * BK];
  __shared__ __align__(16) unsigned short sBh[BN * BK];
  __shared__ __align__(16) unsigned short sAl[SPLIT ? BM * BK : 8];
  __shared__ __align__(16) unsigned short sBl[SPLIT ? BN * BK : 8];

  const int t = threadIdx.x;
  const int ntile = Nh / BN;
  const int bm = blockIdx.x / ntile;
  const int bn = blockIdx.x % ntile;
  const int s = blockIdx.y;
  const int h = blockIdx.z;
  const int H = gridDim.z;

  const unsigned short* Ab = Ah + (size_t)h * strideA_head + (size_t)bm * BM * K;
  const unsigned short* Bb = Bh + (size_t)h * strideB_head + (size_t)bn * BN * K;
  const unsigned short* Alb = SPLIT ? (Al + (size_t)h * strideA_head + (size_t)bm * BM * K) : (const unsigned short*)0;
  const unsigned short* Blb = SPLIT ? (Bl + (size_t)h * strideB_head + (size_t)bn * BN * K) : (const unsigned short*)0;

  int k0 = s * kcSteps * BK;
  int k1 = min(K, k0 + kcSteps * BK);

  const int srow = t >> 2;
  const int gsw = ((t & 3) ^ ((srow >> 1) & 3)) * 8;
  const int lane = t & 63;
  const int wv = t >> 6;
  const int wm = (wv >> 1) * 64;
  const int wn = (wv & 1) * 64;
  const int lr = lane & 15;
  const int q = lane >> 4;
  const int sw = (lr >> 1) & 3;
  const int cA = (q ^ sw) * 8;

  f32x4 acc[4][4];
  const f32x4 z = {0.f, 0.f, 0.f, 0.f};
#pragma unroll
  for (int i = 0; i < 4; ++i)
#pragma unroll
    for (int j = 0; j < 4; ++j) acc[i][j] = z;

  for (int kk = k0; kk < k1; kk += BK) {
#pragma unroll
    for (int j = 0; j < 2; ++j) {
      int row = j * 64 + srow;
      gld_lds16(Ab + (size_t)row * K + kk + gsw, (char*)sAh + j * 4096 + t * 16);
      gld_lds16(Bb + (size_t)row * K + kk + gsw, (char*)sBh + j * 4096 + t * 16);
      if constexpr (SPLIT) {
        gld_lds16(Alb + (size_t)row * K + kk + gsw, (char*)sAl + j * 4096 + t * 16);
        gld_lds16(Blb + (size_t)row * K + kk + gsw, (char*)sBl + j * 4096 + t * 16);
      }
    }
    __syncthreads();

    bf16x8 af[4], bfr[4];
#pragma unroll
    for (int i = 0; i < 4; ++i) af[i] = *(const bf16x8*)&sAh[(wm + i * 16 + lr) * BK + cA];
#pragma unroll
    for (int j = 0; j < 4; ++j) bfr[j] = *(const bf16x8*)&sBh[(wn + j * 16 + lr) * BK + cA];
#pragma unroll
    for (int i = 0; i < 4; ++i)
#pragma unroll
      for (int j = 0; j < 4; ++j)
        acc[i][j] = __builtin_amdgcn_mfma_f32_16x16x32_bf16(af[i], bfr[j], acc[i][j], 0, 0, 0);

    if constexpr (SPLIT) {
      bf16x8 al[4], bl[4];
#pragma unroll
      for (int i = 0; i < 4; ++i) al[i] = *(const bf16x8*)&sAl[(wm + i * 16 + lr) * BK + cA];
#pragma unroll
      for (int j = 0; j < 4; ++j) bl[j] = *(const bf16x8*)&sBl[(wn + j * 16 + lr) * BK + cA];
#pragma unroll
      for (int i = 0; i < 4; ++i)
#pragma unroll
        for (int j = 0; j < 4; ++j) {
          acc[i][j] = __builtin_amdgcn_mfma_f32_16x16x32_bf16(af[i], bl[j], acc[i][j], 0, 0, 0);
          acc[i][j] = __builtin_amdgcn_mfma_f32_16x16x32_bf16(al[i], bfr[j], acc[i][j], 0, 0, 0);
        }
    }
    __syncthreads();
  }

  float* Cb = Cpart + ((size_t)(s * H + h) * MPAD + (size_t)bm * BM) * Nh + (size_t)bn * BN;
#pragma unroll
  for (int i = 0; i < 4; ++i)
#pragma unroll
    for (int j = 0; j < 4; ++j)
#pragma unroll
      for (int r = 0; r < 4; ++r) {
        int m = wm + i * 16 + q * 4 + r;
        int n = wn + j * 16 + lr;
        Cb[(size_t)m * Nh + n] = acc[i][j][r];
      }
}

// ---------------------------------------------------------------------------
// gemm256_bf16 (R6): 256x256 tile, BK=64, 8 waves, 4 phases/K-tile, dbuf,
// counted vmcnt(8). Unsplit; used for stage-2 fused fc1 (N=3072).
// 128B rows: row start bank = 0 for all rows, pg = lg ^ (row&7) covers all
// 8 bank-groups per 16-lane group -> conflict-free (verified by bank math).
// ---------------------------------------------------------------------------
#define DS_A(XB, MH) do { \
    rA[0][0]=lda_f(XB,(MH)*4+0,0); rA[0][1]=lda_f(XB,(MH)*4+0,1); \
    rA[1][0]=lda_f(XB,(MH)*4+1,0); rA[1][1]=lda_f(XB,(MH)*4+1,1); \
    rA[2][0]=lda_f(XB,(MH)*4+2,0); rA[2][1]=lda_f(XB,(MH)*4+2,1); \
    rA[3][0]=lda_f(XB,(MH)*4+3,0); rA[3][1]=lda_f(XB,(MH)*4+3,1); } while(0)

#define DS_B(XB, NH) do { \
    rB[(NH)*2+0][0]=ldb_f(XB,(NH)*2+0,0); rB[(NH)*2+0][1]=ldb_f(XB,(NH)*2+0,1); \
    rB[(NH)*2+1][0]=ldb_f(XB,(NH)*2+1,0); rB[(NH)*2+1][1]=ldb_f(XB,(NH)*2+1,1); } while(0)

#define MFMA_Q(MH, NH) do { \
  _Pragma("unroll") \
  for (int ii = 0; ii < 4; ++ii) { \
    _Pragma("unroll") \
    for (int jj = 0; jj < 2; ++jj) { \
      acc[(MH)*4+ii][(NH)*2+jj] = __builtin_amdgcn_mfma_f32_16x16x32_bf16(rA[ii][0], rB[(NH)*2+jj][0], acc[(MH)*4+ii][(NH)*2+jj], 0, 0, 0); \
      acc[(MH)*4+ii][(NH)*2+jj] = __builtin_amdgcn_mfma_f32_16x16x32_bf16(rA[ii][1], rB[(NH)*2+jj][1], acc[(MH)*4+ii][(NH)*2+jj], 0, 0, 0); \
    } } } while(0)

__global__ __launch_bounds__(512, 2)
void gemm256_bf16(const unsigned short* __restrict__ A,
                  const unsigned short* __restrict__ B,
                  float* __restrict__ Cpart,
                  int Ntot, int K, int tilesTotal)
{
  extern __shared__ char lds[];
  const int t = threadIdx.x;
  const int ntile = Ntot >> 8;
  const int bm = blockIdx.x / ntile;
  const int bn = blockIdx.x % ntile;
  const int s = blockIdx.y;
  const int S = gridDim.y;
  const int qp = tilesTotal / S, rp = tilesTotal % S;
  const int t0 = s * qp + (s < rp ? s : rp);
  const int np = qp + (s < rp ? 1 : 0);

  const unsigned short* Ab = A + (size_t)bm * 256 * K;
  const unsigned short* Bb = B + (size_t)bn * 256 * K;

  const int srow = t >> 3;
  const int sgrp = ((t & 7) ^ (srow & 7)) << 3;

  const int lane = t & 63;
  const int wv = t >> 6;
  const int wm = (wv >> 2) << 7;
  const int wn = (wv & 3) << 6;
  const int lr = lane & 15;
  const int q = lane >> 4;

  f32x4 acc[8][4];
  const f32x4 z = {0.f, 0.f, 0.f, 0.f};
#pragma unroll
  for (int i = 0; i < 8; ++i)
#pragma unroll
    for (int j = 0; j < 4; ++j) acc[i][j] = z;

  bf16x8 rA[4][2], rB[4][2];

  auto stage_tile = [&](int xbuf, int kt) {
    const size_t col = ((size_t)(t0 + kt) << 6) + sgrp;
#pragma unroll
    for (int u = 0; u < 4; ++u) {
      const unsigned short* src = (u < 2) ? Ab : Bb;
      const int rbase = ((u & 1) << 7) + srow;
      char* dst = lds + xbuf * 65536 + ((u & 2) << 14) + ((u & 1) << 14) + t * 16;
      gld_lds16(src + (size_t)rbase * K + col, dst);
      gld_lds16(src + (size_t)(rbase + 64) * K + col, dst + 8192);
    }
  };

  auto lda_f = [&](int xbuf, int i, int ks) -> bf16x8 {
    const int row = wm + (i << 4) + lr;
    const int pg = (ks * 4 + q) ^ (row & 7);
    return *(const bf16x8*)(lds + xbuf * 65536 + row * 128 + pg * 16);
  };
  auto ldb_f = [&](int xbuf, int j, int ks) -> bf16x8 {
    const int row = wn + (j << 4) + lr;
    const int pg = (ks * 4 + q) ^ (row & 7);
    return *(const bf16x8*)(lds + xbuf * 65536 + 32768 + row * 128 + pg * 16);
  };

  stage_tile(0, 0);
  if (np > 1) {
    stage_tile(1, 1);
    asm volatile("s_waitcnt vmcnt(8)" ::: "memory");
  } else {
    asm volatile("s_waitcnt vmcnt(0)" ::: "memory");
  }
  __builtin_amdgcn_s_barrier();

  for (int i = 0; i < np; ++i) {
    const int buf = i & 1;
    const bool st = (i + 2 < np);
    DS_A(buf, 0);
    DS_B(buf, 0);
    PHASE_SYNC();
    __builtin_amdgcn_s_setprio(1);
    MFMA_Q(0, 0);
    PHASE_END();
    DS_B(buf, 1);
    PHASE_SYNC();
    __builtin_amdgcn_s_setprio(1);
    MFMA_Q(0, 1);
    PHASE_END();
    DS_A(buf, 1);
    PHASE_SYNC();
    __builtin_amdgcn_s_setprio(1);
    MFMA_Q(1, 0);
    PHASE_END();
    if (st) {
      stage_tile(buf, i + 2);
      asm volatile("s_waitcnt vmcnt(8)" ::: "memory");
    } else {
      asm volatile("s_waitcnt vmcnt(0)" ::: "memory");
    }
    __builtin_amdgcn_s_barrier();
    __builtin_amdgcn_sched_barrier(0);
    __builtin_amdgcn_s_setprio(1);
    MFMA_Q(1, 1);
    __builtin_amdgcn_s_setprio(0);
  }

  float* Cb = Cpart + (size_t)s * MPAD * Ntot +
              (size_t)(bm * 256 + wm) * Ntot + bn * 256 + wn;
#pragma unroll
  for (int i = 0; i < 8; ++i)
#pragma unroll
    for (int j = 0; j < 4; ++j)
#pragma unroll
      for (int r = 0; r < 4; ++r)
        Cb[(size_t)(i * 16 + q * 4 + r) * Ntot + j * 16 + lr] = acc[i][j][r];
}

// ---------------------------------------------------------------------------
// gemm256s_bf16 (R7, swizzle fixed R8): SPLIT GEMM on the R6 skeleton.
// BM=128 x BN=256 x BK=32, 8 waves (2Mx4N), each wave 64x64 out.
// LDS buf (49152B): Ah@0 (8K), Al@8192, Bh@16384 (16K), Bl@32768; dbuf=96KB.
// Per K-tile: 16 ds_read_b128, 48 MFMA (3 products), 6 gld_lds16.
// R8 swizzle: pg = q ^ ((row>>1)&3) (NOT row&3). With 64B rows the start
// bank alternates 0/16 by row parity; XOR by (row>>1)&3 makes each 16-lane
// group cover all 8 bank-groups (2 lanes/bank = free). Same formula as the
// old 0-conflict kernel. Applied to BOTH staging source and reads.
// (+128 row offset for B's second half preserves (row>>1)&3: 64 mod 4 == 0.)
// ---------------------------------------------------------------------------
#define S_DS_A(XB, MH) do { \
    rAh[0]=s_lda(XB,0,(MH)*2+0); rAh[1]=s_lda(XB,0,(MH)*2+1); \
    rAl[0]=s_lda(XB,1,(MH)*2+0); rAl[1]=s_lda(XB,1,(MH)*2+1); } while(0)

#define S_DS_B(XB, NH) do { \
    rBh[(NH)*2+0]=s_ldb(XB,0,(NH)*2+0); rBh[(NH)*2+1]=s_ldb(XB,0,(NH)*2+1); \
    rBl[(NH)*2+0]=s_ldb(XB,1,(NH)*2+0); rBl[(NH)*2+1]=s_ldb(XB,1,(NH)*2+1); } while(0)

#define S_MFMA_Q(MH, NH) do { \
  _Pragma("unroll") \
  for (int ii = 0; ii < 2; ++ii) { \
    _Pragma("unroll") \
    for (int jj = 0; jj < 2; ++jj) { \
      f32x4* a = &acc[(MH)*2+ii][(NH)*2+jj]; \
      *a = __builtin_amdgcn_mfma_f32_16x16x32_bf16(rAh[ii], rBh[(NH)*2+jj], *a, 0, 0, 0); \
      *a = __builtin_amdgcn_mfma_f32_16x16x32_bf16(rAh[ii], rBl[(NH)*2+jj], *a, 0, 0, 0); \
      *a = __builtin_amdgcn_mfma_f32_16x16x32_bf16(rAl[ii], rBh[(NH)*2+jj], *a, 0, 0, 0); \
    } } } while(0)

__global__ __launch_bounds__(512, 2)
void gemm256s_bf16(const unsigned short* __restrict__ Ah,
                   const unsigned short* __restrict__ Al,
                   const unsigned short* __restrict__ Bh,
                   const unsigned short* __restrict__ Bl,
                   float* __restrict__ Cpart,
                   int Ntot, int K, int tilesTotal)
{
  extern __shared__ char lds[];
  const int t = threadIdx.x;
  const int ntile = Ntot >> 8;                 // N-tiles of 256
  const int bm = blockIdx.x / ntile;           // M-tiles of 128
  const int bn = blockIdx.x % ntile;
  const int s = blockIdx.y;
  const int S = gridDim.y;
  const int qp = tilesTotal / S, rp = tilesTotal % S;
  const int t0 = s * qp + (s < rp ? s : rp);
  const int np = qp + (s < rp ? 1 : 0);

  const unsigned short* Ahb = Ah + (size_t)bm * 128 * K;
  const unsigned short* Alb = Al + (size_t)bm * 128 * K;
  const unsigned short* Bhb = Bh + (size_t)bn * 256 * K;
  const unsigned short* Blb = Bl + (size_t)bn * 256 * K;

  // staging: 64B rows, 4 threads/row; physical slot (row, pg=t&3) holds
  // logical group (t&3)^((row>>1)&3) -> pre-swizzled global source column.
  const int srow = t >> 2;                         // 0..127
  const int sgrp = ((t & 3) ^ ((srow >> 1) & 3)) << 3;  // R8 fix

  const int lane = t & 63;
  const int wv = t >> 6;
  const int wm = (wv >> 2) << 6;   // 0 / 64
  const int wn = (wv & 3) << 6;    // 0 / 64 / 128 / 192
  const int lr = lane & 15;
  const int q = lane >> 4;

  f32x4 acc[4][4];
  const f32x4 z = {0.f, 0.f, 0.f, 0.f};
#pragma unroll
  for (int i = 0; i < 4; ++i)
#pragma unroll
    for (int j = 0; j < 4; ++j) acc[i][j] = z;

  bf16x8 rAh[2], rAl[2], rBh[4], rBl[4];

  // 6 gld_lds16 per thread per K-tile
  auto stage_tile = [&](int xbuf, int kt) {
    const size_t col = ((size_t)(t0 + kt) << 5) + sgrp;
    char* base = lds + xbuf * 49152;
    gld_lds16(Ahb + (size_t)srow * K + col, base + t * 16);
    gld_lds16(Alb + (size_t)srow * K + col, base + 8192 + t * 16);
    gld_lds16(Bhb + (size_t)srow * K + col, base + 16384 + t * 16);
    gld_lds16(Bhb + (size_t)(srow + 128) * K + col, base + 16384 + 8192 + t * 16);
    gld_lds16(Blb + (size_t)srow * K + col, base + 32768 + t * 16);
    gld_lds16(Blb + (size_t)(srow + 128) * K + col, base + 32768 + 8192 + t * 16);
  };

  auto s_lda = [&](int xbuf, int pl, int i) -> bf16x8 {
    const int row = wm + (i << 4) + lr;          // 0..127
    const int pg = q ^ ((row >> 1) & 3);         // R8 fix
    return *(const bf16x8*)(lds + xbuf * 49152 + pl * 8192 + row * 64 + pg * 16);
  };
  auto s_ldb = [&](int xbuf, int pl, int j) -> bf16x8 {
    const int row = wn + (j << 4) + lr;          // 0..255
    const int pg = q ^ ((row >> 1) & 3);         // R8 fix
    return *(const bf16x8*)(lds + xbuf * 49152 + 16384 + pl * 16384 + row * 64 + pg * 16);
  };

  // prologue: tile0 -> buf0, tile1 -> buf1; counted wait for tile0
  stage_tile(0, 0);
  if (np > 1) {
    stage_tile(1, 1);
    asm volatile("s_waitcnt vmcnt(6)" ::: "memory");
  } else {
    asm volatile("s_waitcnt vmcnt(0)" ::: "memory");
  }
  __builtin_amdgcn_s_barrier();

  for (int i = 0; i < np; ++i) {
    const int buf = i & 1;
    const bool st = (i + 2 < np);
    // P1: A half0 (4) + B group0 (8) ds_reads; Q(0,0) 12 MFMA
    S_DS_A(buf, 0);
    S_DS_B(buf, 0);
    PHASE_SYNC();
    __builtin_amdgcn_s_setprio(1);
    S_MFMA_Q(0, 0);
    PHASE_END();
    // P2: B group1; Q(0,1)
    S_DS_B(buf, 1);
    PHASE_SYNC();
    __builtin_amdgcn_s_setprio(1);
    S_MFMA_Q(0, 1);
    PHASE_END();
    // P3: A half1; Q(1,0)
    S_DS_A(buf, 1);
    PHASE_SYNC();
    __builtin_amdgcn_s_setprio(1);
    S_MFMA_Q(1, 0);
    PHASE_END();
    // P4: stage tile i+2 (WAR-safe: all reads of buf done at P3 END barrier),
    //     counted vmcnt(6) = tile i+1 landed, i+2 in flight; barrier; Q(1,1).
    if (st) {
      stage_tile(buf, i + 2);
      asm volatile("s_waitcnt vmcnt(6)" ::: "memory");
    } else {
      asm volatile("s_waitcnt vmcnt(0)" ::: "memory");
    }
    __builtin_amdgcn_s_barrier();
    __builtin_amdgcn_sched_barrier(0);
    __builtin_amdgcn_s_setprio(1);
    S_MFMA_Q(1, 1);
    __builtin_amdgcn_s_setprio(0);
  }

  float* Cb = Cpart + (size_t)s * MPAD * Ntot +
              (size_t)(bm * 128 + wm) * Ntot + bn * 256 + wn;
#pragma unroll
  for (int i = 0; i < 4; ++i)
#pragma unroll
    for (int j = 0; j < 4; ++j)
#pragma unroll
      for (int r = 0; r < 4; ++r)
        Cb[(size_t)(i * 16 + q * 4 + r) * Ntot + j * 16 + lr] = acc[i][j][r];
}

// ---------------------------------------------------------------------------
// Epilogue (x4 vectorized): v = relu(sum_s partial + bias), emit bf16 hi[,lo].
// ---------------------------------------------------------------------------
__global__ __launch_bounds__(256)
void epilogue_kernel(const float* __restrict__ Cpart, int S, int H, int Nh,
                     const float* __restrict__ bias,
                     unsigned short* __restrict__ ohi,
                     unsigned short* __restrict__ olo, int flags)
{
  size_t total = (size_t)H * MPAD * Nh;
  size_t idx = ((size_t)blockIdx.x * 256 + threadIdx.x) * 4;
  if (idx >= total) return;
  int n = (int)(idx % Nh);
  int h = (int)(idx / ((size_t)MPAD * Nh));
  f32x4 v = *(const f32x4*)&bias[(size_t)h * Nh + n];
  for (int s = 0; s < S; ++s) v += *(const f32x4*)&Cpart[(size_t)s * total + idx];
  u16x4 hi, lo;
#pragma unroll
  for (int j = 0; j < 4; ++j) {
    float x = fmaxf(v[j], 0.f);
    hi[j] = f2bf(x);
    lo[j] = f2bf(x - bf2f(hi[j]));
  }
  *(u16x4*)&ohi[idx] = hi;
  if (flags & 4) *(u16x4*)&olo[idx] = lo;
}

// Epilogue for stage-2 fused fc1 (N=3072): partials [s][1024][3072],
// de-interleave into h1_hi[h][1024][1024]. bias = fc1_b (3x1024 contiguous).
__global__ __launch_bounds__(256)
void epilogue_fc1_s2(const float* __restrict__ Cpart, int S,
                     const float* __restrict__ bias,
                     unsigned short* __restrict__ ohi)
{
  const size_t total = (size_t)MPAD * 3072;
  size_t idx = ((size_t)blockIdx.x * 256 + threadIdx.x) * 4;
  if (idx >= total) return;
  int n = (int)(idx % 3072);
  int m = (int)(idx / 3072);
  f32x4 v = *(const f32x4*)&bias[n];
  for (int s = 0; s < S; ++s) v += *(const f32x4*)&Cpart[(size_t)s * total + idx];
  u16x4 hi;
#pragma unroll
  for (int j = 0; j < 4; ++j) hi[j] = f2bf(fmaxf(v[j], 0.f));
  int h = n >> 10;
  *(u16x4*)&ohi[((size_t)h * MPAD + m) * 1024 + (n & 1023)] = hi;
}

// ---------------------------------------------------------------------------
// Transpose + fp32->bf16 hi/lo: W[H][K][N] -> T[H][N][K].
// ---------------------------------------------------------------------------
__global__ __launch_bounds__(256)
void transpose_convert(const float* __restrict__ W,
                       unsigned short* __restrict__ Thi,
                       unsigned short* __restrict__ Tlo,
                       int K, int N, int loHeads)
{
  __shared__ float tile[32][260];
  int kb = blockIdx.x * 256;
  int nb = blockIdx.y * 32;
  int h = blockIdx.z;
  const float* Wb = W + (size_t)h * K * N + (size_t)kb * N + nb;
  int tn = threadIdx.x & 31;
  int tk = threadIdx.x >> 5;
#pragma unroll
  for (int i = 0; i < 32; ++i) {
    int k = tk + i * 8;
    tile[tn][k] = Wb[(size_t)k * N + tn];
  }
  __syncthreads();
  bool wlo = h < loHeads;
  int l = threadIdx.x & 63;
  int ng = threadIdx.x >> 6;
  size_t ob = (size_t)h * N * K + (size_t)nb * K + kb;
#pragma unroll
  for (int i = 0; i < 8; ++i) {
    int n = ng + i * 4;
    f32x4 v = *(const f32x4*)&tile[n][4 * l];
    u16x4 hi;
#pragma unroll
    for (int j = 0; j < 4; ++j) hi[j] = f2bf(v[j]);
    *(u16x4*)&Thi[ob + (size_t)n * K + 4 * l] = hi;
    if (wlo) {
      u16x4 lo;
#pragma unroll
      for (int j = 0; j < 4; ++j) lo[j] = f2bf(v[j] - bf2f(hi[j]));
      *(u16x4*)&Tlo[ob + (size_t)n * K + 4 * l] = lo;
    }
  }
}

// cls_w (3,1024,81) -> w3t (3,128,1024) bf16, rows 81..127 zero. grid (128,3).
__global__ void transpose_cls(const float* __restrict__ W, unsigned short* __restrict__ T)
{
  int n = blockIdx.x, h = blockIdx.y, t = threadIdx.x;
  size_t ob = ((size_t)h * 128 + n) * 1024;
  if (n < 81) {
    for (int k = t; k < 1024; k += 256)
      T[ob + k] = f2bf(W[((size_t)h * 1024 + k) * 81 + n]);
  } else {
    for (int k = t; k < 1024; k += 256) T[ob + k] = 0;
  }
}

// ---------------------------------------------------------------------------
// Pyramid ROI-align: one block per roi; 64 channel-quads x 4 position groups.
// ---------------------------------------------------------------------------
__global__ void roi_align_kernel(const float* __restrict__ rois,
                                 const float* __restrict__ P2, const float* __restrict__ P3,
                                 const float* __restrict__ P4, const float* __restrict__ P5,
                                 unsigned short* __restrict__ phi,
                                 unsigned short* __restrict__ plo, int writeLo)
{
  int m = blockIdx.x;
  int t = threadIdx.x;
  int c = (t & 63) * 4;
  int pg = t >> 6;  // 0..3
  const float* rp = rois + m * 4;
  float y1 = rp[0], x1 = rp[1], y2 = rp[2], x2 = rp[3];
  float hh = y2 - y1, ww = x2 - x1;
  float a = sqrtf(fmaxf(hh * ww, 1e-6f)) / 224.0f;
  float lvl = floorf(4.0f + log2f(a));
  lvl = fminf(fmaxf(lvl, 2.0f), 5.0f);
  int i = (int)lvl - 2;
  const float* f = (i == 0) ? P2 : (i == 1) ? P3 : (i == 2) ? P4 : P5;
  int H = 256 >> i;
  float stride = (float)(4 << i);
  float sy1 = y1 / stride, sx1 = x1 / stride;
  float dy = y2 / stride - sy1, dx = x2 / stride - sx1;
  size_t base = (size_t)m * K1 + c;
  for (int p = pg; p < 49; p += 4) {
    int py = p / 7, px = p % 7;
    float ys = sy1 + ((py + 0.5f) / 7.0f) * dy;
    float xs = sx1 + ((px + 0.5f) / 7.0f) * dx;
    float y0f = fminf(fmaxf(floorf(ys), 0.0f), (float)(H - 1));
    float x0f = fminf(fmaxf(floorf(xs), 0.0f), (float)(H - 1));
    int y0 = (int)y0f, x0 = (int)x0f;
    int y1i = min(y0 + 1, H - 1), x1i = min(x0 + 1, H - 1);
    float wy = fminf(fmaxf(ys - y0f, 0.0f), 1.0f);
    float wx = fminf(fmaxf(xs - x0f, 0.0f), 1.0f);
    f32x4 v00 = *(const f32x4*)(f + ((size_t)y0 * H + x0) * 256 + c);
    f32x4 v01 = *(const f32x4*)(f + ((size_t)y0 * H + x1i) * 256 + c);
    f32x4 v10 = *(const f32x4*)(f + ((size_t)y1i * H + x0) * 256 + c);
    f32x4 v11 = *(const f32x4*)(f + ((size_t)y1i * H + x1i) * 256 + c);
    float w00 = (1.f - wy) * (1.f - wx), w01 = (1.f - wy) * wx;
    float w10 = wy * (1.f - wx), w11 = wy * wx;
    f32x4 v = v00 * w00 + v01 * w01 + v10 * w10 + v11 * w11;
    u16x4 hi;
#pragma unroll
    for (int j = 0; j < 4; ++j) hi[j] = f2bf(v[j]);
    *(u16x4*)&phi[base + p * 256] = hi;
    if (writeLo) {
      u16x4 lo;
#pragma unroll
      for (int j = 0; j < 4; ++j) lo[j] = f2bf(v[j] - bf2f(hi[j]));
      *(u16x2*)&plo[base + p * 256] = *(u16x2*)&lo;
      *(u16x2*)&plo[base + p * 256 + 2] = *((u16x2*)&lo + 1);
    }
  }
}

// ---------------------------------------------------------------------------
// FUSED fc2-epilogue + reg head + delta2bbox (stages 0/1).
// ---------------------------------------------------------------------------
__global__ void reg_delta_kernel(const float* __restrict__ Cpart, int S,
                                 const float* __restrict__ fb,
                                 const float* __restrict__ rw, const float* __restrict__ rb,
                                 const float* __restrict__ rin, float* __restrict__ rout)
{
  int m = blockIdx.x, t = threadIdx.x;
  float s0 = 0, s1 = 0, s2 = 0, s3 = 0;
  for (int n = t; n < 1024; n += 256) {
    float v = fb[n];
    for (int s = 0; s < S; ++s) v += Cpart[((size_t)s * 1024 + m) * 1024 + n];
    v = fmaxf(v, 0.f);
    const float* w = rw + (size_t)n * 4;
    s0 += v * w[0]; s1 += v * w[1]; s2 += v * w[2]; s3 += v * w[3];
  }
#pragma unroll
  for (int o = 32; o > 0; o >>= 1) {
    s0 += __shfl_xor(s0, o, 64);
    s1 += __shfl_xor(s1, o, 64);
    s2 += __shfl_xor(s2, o, 64);
    s3 += __shfl_xor(s3, o, 64);
  }
  __shared__ float part[4][4];
  int w = t >> 6;
  if ((t & 63) == 0) { part[w][0] = s0; part[w][1] = s1; part[w][2] = s2; part[w][3] = s3; }
  __syncthreads();
  if (t == 0) {
    float d0 = (part[0][0] + part[1][0] + part[2][0] + part[3][0] + rb[0]) * 0.1f;
    float d1 = (part[0][1] + part[1][1] + part[2][1] + part[3][1] + rb[1]) * 0.1f;
    float d2 = (part[0][2] + part[1][2] + part[2][2] + part[3][2] + rb[2]) * 0.2f;
    float d3 = (part[0][3] + part[1][3] + part[2][3] + part[3][3] + rb[3]) * 0.2f;
    const float* r = rin + m * 4;
    float y1 = r[0], x1 = r[1], y2 = r[2], x2 = r[3];
    float h = y2 - y1, wd = x2 - x1;
    float cy = y1 + 0.5f * h + d0 * h;
    float cx = x1 + 0.5f * wd + d1 * wd;
    float nh = h * expf(d2);
    float nw = wd * expf(d3);
    float* ro = rout + m * 4;
    ro[0] = fminf(fmaxf(cy - 0.5f * nh, 0.f), 1024.f);
    ro[1] = fminf(fmaxf(cx - 0.5f * nw, 0.f), 1024.f);
    ro[2] = fminf(fmaxf(cy + 0.5f * nh, 0.f), 1024.f);
    ro[3] = fminf(fmaxf(cx + 0.5f * nw, 0.f), 1024.f);
  }
}

// ---------------------------------------------------------------------------
// FUSED cls-epilogue + softmax + 3-head average.
// ---------------------------------------------------------------------------
__global__ void softmax_avg_kernel(const float* __restrict__ Cpart, int S,
                                   const float* __restrict__ cls_b,
                                   float* __restrict__ out)
{
  int m = blockIdx.x, t = threadIdx.x;
  __shared__ float sh[128];
  float pacc = 0.0f;
  for (int h = 0; h < 3; ++h) {
    float x = -3.0e38f;
    if (t < 81) {
      x = cls_b[h * 81 + t];
      for (int s = 0; s < S; ++s)
        x += Cpart[((size_t)(s * 3 + h) * 1024 + m) * 128 + t];
    }
    sh[t] = x; __syncthreads();
    for (int o = 64; o > 0; o >>= 1) { if (t < o) sh[t] = fmaxf(sh[t], sh[t + o]); __syncthreads(); }
    float mx = sh[0]; __syncthreads();
    float e = (t < 81) ? expf(x - mx) : 0.0f;
    sh[t] = e; __syncthreads();
    for (int o = 64; o > 0; o >>= 1) { if (t < o) sh[t] += sh[t + o]; __syncthreads(); }
    float sum = sh[0]; __syncthreads();
    pacc += e / sum;
  }
  if (t < 81) out[(size_t)m * 81 + t] = pacc / 3.0f;
}

// ===========================================================================
extern "C" void kernel_launch(void* const* d_in, const int* in_sizes, int n_in,
                              void* d_out, int out_size, void* d_ws, size_t ws_size,
                              hipStream_t stream)
{
  const float* P2 = (const float*)d_in[0];
  const float* P3 = (const float*)d_in[1];
  const float* P4 = (const float*)d_in[2];
  const float* P5 = (const float*)d_in[3];
  const float* rois = (const float*)d_in[4];
  const float* fc1_w = (const float*)d_in[5];
  const float* fc1_b = (const float*)d_in[6];
  const float* fc2_w = (const float*)d_in[7];
  const float* fc2_b = (const float*)d_in[8];
  const float* cls_w = (const float*)d_in[9];
  const float* cls_b = (const float*)d_in[10];
  const float* reg_w = (const float*)d_in[11];
  const float* reg_b = (const float*)d_in[12];
  float* out = (float*)d_out;

  char* ws = (char*)d_ws;
  size_t off = 0;
  auto alloc = [&](size_t b) -> char* {
    char* p = ws + off;
    off = (off + b + 255) & ~(size_t)255;
    return p;
  };
  unsigned short* w1t_hi = (unsigned short*)alloc(3ull * 1024 * K1 * 2);
  unsigned short* w2t_hi = (unsigned short*)alloc(3ull * 1024 * 1024 * 2);
  unsigned short* w2t_lo = (unsigned short*)alloc(2ull * 1024 * 1024 * 2);
  unsigned short* w3t    = (unsigned short*)alloc(3ull * 128 * 1024 * 2);
  unsigned short* phi    = (unsigned short*)alloc((size_t)MPAD * K1 * 2);
  unsigned short* plo    = (unsigned short*)alloc((size_t)MPAD * K1 * 2);
  unsigned short* h1_hi  = (unsigned short*)alloc(3ull * MPAD * 1024 * 2);
  unsigned short* h1_lo  = (unsigned short*)alloc((size_t)MPAD * 1024 * 2);
  unsigned short* h2_hi  = (unsigned short*)alloc(3ull * MPAD * 1024 * 2);
  float* r1              = (float*)alloc(16384);
  float* r2              = (float*)alloc(16384);
  // w1t_lo LAST: dead after stage 1, so stage-2 partials reuse it + tail.
  const size_t w1lo_bytes = 2ull * 1024 * K1 * 2;
  unsigned short* w1t_lo = (unsigned short*)alloc(w1lo_bytes);

  const size_t SLAB = (size_t)MPAD * 1024 * 4;  // 4 MiB per (s,h) slice
  size_t tail = (ws_size > off) ? (ws_size - off) : 0;

  // stages 0/1 partials in tail; R2-proven sweet spot S=8
  int S01 = (int)(tail / SLAB);
  if (S01 > 8) S01 = 8;
  if (S01 < 1) S01 = 1;
  float* cpart01 = (float*)(ws + off);
  // stage-2 partials alias w1t_lo + tail
  const int S2 = 4;
  float* cpart2 = (float*)w1t_lo;

  const int fc2Steps01 = (32 + S01 - 1) / S01;

  const long long hs1 = (long long)1024 * K1;
  const long long hs2 = (long long)1024 * 1024;

  dim3 b256(256);

  // --- weight conversion (per call) ---
  hipLaunchKernelGGL(transpose_convert, dim3(K1 / 256, 32, 3), b256, 0, stream,
                     fc1_w, w1t_hi, w1t_lo, K1, 1024, 2);
  hipLaunchKernelGGL(transpose_convert, dim3(4, 32, 3), b256, 0, stream,
                     fc2_w, w2t_hi, w2t_lo, 1024, 1024, 2);
  hipLaunchKernelGGL(transpose_cls, dim3(128, 3), b256, 0, stream, cls_w, w3t);
  hipMemsetAsync(phi + (size_t)NROI * K1, 0, (size_t)(MPAD - NROI) * K1 * 2, stream);
  hipMemsetAsync(plo + (size_t)NROI * K1, 0, (size_t)(MPAD - NROI) * K1 * 2, stream);

  // --- stages 0,1: split-precision path, deltas only ---
  for (int st = 0; st < 2; ++st) {
    const float* rin = (st == 0) ? rois : r1;
    float* rout = (st == 0) ? r1 : r2;
    hipLaunchKernelGGL(roi_align_kernel, dim3(NROI), b256, 0, stream,
                       rin, P2, P3, P4, P5, phi, plo, 1);
    // SPLIT fc1 on gemm256s: grid 32 x S01(=8) = 256 blocks = 1/CU.
    hipLaunchKernelGGL(gemm256s_bf16, dim3(32, S01), dim3(512), 98304, stream,
                       phi, plo,
                       w1t_hi + (size_t)st * hs1, w1t_lo + (size_t)st * hs1,
                       cpart01, 1024, K1, 392);
    hipLaunchKernelGGL(epilogue_kernel, dim3(1024), b256, 0, stream,
                       cpart01, S01, 1, 1024, fc1_b + st * 1024,
                       h1_hi, h1_lo, 4);
    hipLaunchKernelGGL((gemm_bf16<true>), dim3(64, S01, 1), b256, 0, stream,
                       h1_hi, h1_lo, 0LL,
                       w2t_hi + (size_t)st * hs2, w2t_lo + (size_t)st * hs2, 0LL,
                       cpart01, 1024, 1024, fc2Steps01);
    hipLaunchKernelGGL(reg_delta_kernel, dim3(NROI), b256, 0, stream,
                       cpart01, S01, fc2_b + st * 1024,
                       reg_w + (size_t)st * 1024 * 4, reg_b + st * 4,
                       rin, rout);
  }

  // --- stage 2 ---
  hipLaunchKernelGGL(roi_align_kernel, dim3(NROI), b256, 0, stream,
                     r2, P2, P3, P4, P5, phi, plo, 0);
  // fc1 for heads 0,1,2 as ONE fused GEMM: M=1024, N=3072 on gemm256_bf16.
  {
    const size_t SLAB3 = (size_t)MPAD * 3072 * 4;
    size_t availC2 = ws_size - (size_t)((char*)w1t_lo - ws);
    int S2f = 5;
    while (S2f > 1 && (size_t)S2f * SLAB3 > availC2) --S2f;
    hipLaunchKernelGGL(gemm256_bf16, dim3(48, S2f), dim3(512), 131072, stream,
                       phi, w1t_hi, cpart2, 3072, K1, 196);
    hipLaunchKernelGGL(epilogue_fc1_s2, dim3(3072), b256, 0, stream,
                       cpart2, S2f, fc1_b, h1_hi);
  }
  // fc2: heads batched via blockIdx.z on the 128^2 kernel.
  hipLaunchKernelGGL((gemm_bf16<false>), dim3(64, S2, 3), b256, 0, stream,
                     h1_hi, (const unsigned short*)0, hs2,
                     w2t_hi, (const unsigned short*)0, hs2,
                     cpart2, 1024, 1024, (32 + S2 - 1) / S2);
  hipLaunchKernelGGL(epilogue_kernel, dim3(3072), b256, 0, stream,
                     cpart2, S2, 3, 1024, fc2_b,
                     h2_hi, (unsigned short*)0, 0);
  // cls: N=128 (81 real + pad), S=8 -> 192 blocks, 4 steps
  hipLaunchKernelGGL((gemm_bf16<false>), dim3(8, 8, 3), b256, 0, stream,
                     h2_hi, (const unsigned short*)0, hs2,
                     w3t, (const unsigned short*)0, (long long)128 * 1024,
                     cpart2, 128, 1024, 4);
  hipLaunchKernelGGL(softmax_avg_kernel, dim3(NROI), dim3(128), 0, stream,
                     cpart2, 8, cls_b, out);
}

// Round 5
// 783.681 us; speedup vs baseline: 1.0780x; 1.0039x over previous
//
#include <hip/hip_runtime.h>

// ============================================================================
// CascadeRCNN: 3-stage cascade of {pyramid ROI-align -> fc1 -> fc2 -> heads}
//  - Stages 0/1: SPLIT bf16 (hi+lo, 3 MFMA products) fc1/fc2 -> fp32-accurate
//    reg deltas (they feed the discontinuous pyramid-level select).
//  - R9: gemm256s restructured from 4 lockstep phases to a 1-tile-deep
//    software pipeline with DOUBLE fragment register sets:
//      per tile i (cur=i&1):
//        stage tile i+2 -> buf[cur]; vmcnt(6); barrier;
//        issue all 16 ds_reads buf[cur^1] -> set[cur^1];
//        48 MFMA on set[cur];            // reads drain UNDER the MFMA
//        lgkmcnt(0); barrier;            // globalize -> next stage WAR-safe
//    R8's 4632 cyc/tile was 4x(read-drain SERIAL with MFMA); floor is
//    max(MFMA 1863, LDS 1536) cyc/tile. 2 barriers/tile (was 8).
//    WAR proof: buf[cur]'s reads were issued last iteration and drained at
//    its lgkmcnt(0)+barrier, so staging into buf[cur] this iteration is safe.
//    RAW proof: vmcnt(6) (=tile i+2's 6 loads outstanding) + barrier proves
//    tile i+1 landed in buf[cur^1] before its ds_reads issue.
//  - R8: swizzle pg = q ^ ((row>>1)&3) both-sides (conflicts 6.4M -> 0).
//  - Stage 2: fc1 heads fused M=1024xN=3072 on gemm256_bf16 (R6, 256^2 BK64).
//  - fc2/cls stay on the 128^2 kernel.
// ============================================================================

#define BM 128
#define BN 128
#define BK 32
#define K1 12544
#define MPAD 1024
#define NROI 1000

typedef __bf16 bf16_t;
typedef bf16_t bf16x8 __attribute__((ext_vector_type(8)));
typedef float f32x4 __attribute__((ext_vector_type(4)));
typedef float f32x2 __attribute__((ext_vector_type(2)));
typedef unsigned short u16x4 __attribute__((ext_vector_type(4)));
typedef unsigned short u16x2 __attribute__((ext_vector_type(2)));

__device__ __forceinline__ unsigned short f2bf(float x) {
  unsigned u = __float_as_uint(x);
  return (unsigned short)((u + 0x7fffu + ((u >> 16) & 1u)) >> 16);
}
__device__ __forceinline__ float bf2f(unsigned short h) {
  return __uint_as_float(((unsigned)h) << 16);
}

__device__ __forceinline__ void gld_lds16(const void* g, void* l) {
  __builtin_amdgcn_global_load_lds(
      (__attribute__((address_space(1))) void*)g,
      (__attribute__((address_space(3))) void*)l, 16, 0, 0);
}

#define PHASE_SYNC() do { \
  __builtin_amdgcn_s_barrier(); \
  asm volatile("s_waitcnt lgkmcnt(0)" ::: "memory"); \
  __builtin_amdgcn_sched_barrier(0); } while(0)

#define PHASE_END() do { \
  __builtin_amdgcn_s_setprio(0); \
  __builtin_amdgcn_s_barrier(); } while(0)

// ---------------------------------------------------------------------------
// OLD GEMM (128x128x32, 4 waves): kept for split fc2 and stage-2 fc2/cls.
// ---------------------------------------------------------------------------
template <bool SPLIT>
__global__ __launch_bounds__(256, 4)
void gemm_bf16(const unsigned short* __restrict__ Ah,
               const unsigned short* __restrict__ Al,
               long long strideA_head,
               const unsigned short* __restrict__ Bh,
               const unsigned short* __restrict__ Bl,
               long long strideB_head,
               float* __restrict__ Cpart,
               int Nh, int K, int kcSteps)
{
  __shared__ __align__(16) unsigned short sAh[BM * BK];
  __shared__ __align__(16) unsigned short sBh[BN * BK];
  __shared__ __align__(16) unsigned short sAl[SPLIT ? BM * BK : 8];
  __shared__ __align__(16) unsigned short sBl[SPLIT ? BN * BK : 8];

  const int t = threadIdx.x;
  const int ntile = Nh / BN;
  const int bm = blockIdx.x / ntile;
  const int bn = blockIdx.x % ntile;
  const int s = blockIdx.y;
  const int h = blockIdx.z;
  const int H = gridDim.z;

  const unsigned short* Ab = Ah + (size_t)h * strideA_head + (size_t)bm * BM * K;
  const unsigned short* Bb = Bh + (size_t)h * strideB_head + (size_t)bn * BN * K;
  const unsigned short* Alb = SPLIT ? (Al + (size_t)h * strideA_head + (size_t)bm * BM * K) : (const unsigned short*)0;
  const unsigned short* Blb = SPLIT ? (Bl + (size_t)h * strideB_head + (size_t)bn * BN * K) : (const unsigned short*)0;

  int k0 = s * kcSteps * BK;
  int k1 = min(K, k0 + kcSteps * BK);

  const int srow = t >> 2;
  const int gsw = ((t & 3) ^ ((srow >> 1) & 3)) * 8;
  const int lane = t & 63;
  const int wv = t >> 6;
  const int wm = (wv >> 1) * 64;
  const int wn = (wv & 1) * 64;
  const int lr = lane & 15;
  const int q = lane >> 4;
  const int sw = (lr >> 1) & 3;
  const int cA = (q ^ sw) * 8;

  f32x4 acc[4][4];
  const f32x4 z = {0.f, 0.f, 0.f, 0.f};
#pragma unroll
  for (int i = 0; i < 4; ++i)
#pragma unroll
    for (int j = 0; j < 4; ++j) acc[i][j] = z;

  for (int kk = k0; kk < k1; kk += BK) {
#pragma unroll
    for (int j = 0; j < 2; ++j) {
      int row = j * 64 + srow;
      gld_lds16(Ab + (size_t)row * K + kk + gsw, (char*)sAh + j * 4096 + t * 16);
      gld_lds16(Bb + (size_t)row * K + kk + gsw, (char*)sBh + j * 4096 + t * 16);
      if constexpr (SPLIT) {
        gld_lds16(Alb + (size_t)row * K + kk + gsw, (char*)sAl + j * 4096 + t * 16);
        gld_lds16(Blb + (size_t)row * K + kk + gsw, (char*)sBl + j * 4096 + t * 16);
      }
    }
    __syncthreads();

    bf16x8 af[4], bfr[4];
#pragma unroll
    for (int i = 0; i < 4; ++i) af[i] = *(const bf16x8*)&sAh[(wm + i * 16 + lr) * BK + cA];
#pragma unroll
    for (int j = 0; j < 4; ++j) bfr[j] = *(const bf16x8*)&sBh[(wn + j * 16 + lr) * BK + cA];
#pragma unroll
    for (int i = 0; i < 4; ++i)
#pragma unroll
      for (int j = 0; j < 4; ++j)
        acc[i][j] = __builtin_amdgcn_mfma_f32_16x16x32_bf16(af[i], bfr[j], acc[i][j], 0, 0, 0);

    if constexpr (SPLIT) {
      bf16x8 al[4], bl[4];
#pragma unroll
      for (int i = 0; i < 4; ++i) al[i] = *(const bf16x8*)&sAl[(wm + i * 16 + lr) * BK + cA];
#pragma unroll
      for (int j = 0; j < 4; ++j) bl[j] = *(const bf16x8*)&sBl[(wn + j * 16 + lr) * BK + cA];
#pragma unroll
      for (int i = 0; i < 4; ++i)
#pragma unroll
        for (int j = 0; j < 4; ++j) {
          acc[i][j] = __builtin_amdgcn_mfma_f32_16x16x32_bf16(af[i], bl[j], acc[i][j], 0, 0, 0);
          acc[i][j] = __builtin_amdgcn_mfma_f32_16x16x32_bf16(al[i], bfr[j], acc[i][j], 0, 0, 0);
        }
    }
    __syncthreads();
  }

  float* Cb = Cpart + ((size_t)(s * H + h) * MPAD + (size_t)bm * BM) * Nh + (size_t)bn * BN;
#pragma unroll
  for (int i = 0; i < 4; ++i)
#pragma unroll
    for (int j = 0; j < 4; ++j)
#pragma unroll
      for (int r = 0; r < 4; ++r) {
        int m = wm + i * 16 + q * 4 + r;
        int n = wn + j * 16 + lr;
        Cb[(size_t)m * Nh + n] = acc[i][j][r];
      }
}

// ---------------------------------------------------------------------------
// gemm256_bf16 (R6): 256x256 tile, BK=64, 8 waves, 4 phases/K-tile, dbuf,
// counted vmcnt(8). Unsplit; used for stage-2 fused fc1 (N=3072).
// (Not pipelined like gemm256s: double reg set would need ~350 regs.)
// ---------------------------------------------------------------------------
#define DS_A(XB, MH) do { \
    rA[0][0]=lda_f(XB,(MH)*4+0,0); rA[0][1]=lda_f(XB,(MH)*4+0,1); \
    rA[1][0]=lda_f(XB,(MH)*4+1,0); rA[1][1]=lda_f(XB,(MH)*4+1,1); \
    rA[2][0]=lda_f(XB,(MH)*4+2,0); rA[2][1]=lda_f(XB,(MH)*4+2,1); \
    rA[3][0]=lda_f(XB,(MH)*4+3,0); rA[3][1]=lda_f(XB,(MH)*4+3,1); } while(0)

#define DS_B(XB, NH) do { \
    rB[(NH)*2+0][0]=ldb_f(XB,(NH)*2+0,0); rB[(NH)*2+0][1]=ldb_f(XB,(NH)*2+0,1); \
    rB[(NH)*2+1][0]=ldb_f(XB,(NH)*2+1,0); rB[(NH)*2+1][1]=ldb_f(XB,(NH)*2+1,1); } while(0)

#define MFMA_Q(MH, NH) do { \
  _Pragma("unroll") \
  for (int ii = 0; ii < 4; ++ii) { \
    _Pragma("unroll") \
    for (int jj = 0; jj < 2; ++jj) { \
      acc[(MH)*4+ii][(NH)*2+jj] = __builtin_amdgcn_mfma_f32_16x16x32_bf16(rA[ii][0], rB[(NH)*2+jj][0], acc[(MH)*4+ii][(NH)*2+jj], 0, 0, 0); \
      acc[(MH)*4+ii][(NH)*2+jj] = __builtin_amdgcn_mfma_f32_16x16x32_bf16(rA[ii][1], rB[(NH)*2+jj][1], acc[(MH)*4+ii][(NH)*2+jj], 0, 0, 0); \
    } } } while(0)

__global__ __launch_bounds__(512, 2)
void gemm256_bf16(const unsigned short* __restrict__ A,
                  const unsigned short* __restrict__ B,
                  float* __restrict__ Cpart,
                  int Ntot, int K, int tilesTotal)
{
  extern __shared__ char lds[];
  const int t = threadIdx.x;
  const int ntile = Ntot >> 8;
  const int bm = blockIdx.x / ntile;
  const int bn = blockIdx.x % ntile;
  const int s = blockIdx.y;
  const int S = gridDim.y;
  const int qp = tilesTotal / S, rp = tilesTotal % S;
  const int t0 = s * qp + (s < rp ? s : rp);
  const int np = qp + (s < rp ? 1 : 0);

  const unsigned short* Ab = A + (size_t)bm * 256 * K;
  const unsigned short* Bb = B + (size_t)bn * 256 * K;

  const int srow = t >> 3;
  const int sgrp = ((t & 7) ^ (srow & 7)) << 3;

  const int lane = t & 63;
  const int wv = t >> 6;
  const int wm = (wv >> 2) << 7;
  const int wn = (wv & 3) << 6;
  const int lr = lane & 15;
  const int q = lane >> 4;

  f32x4 acc[8][4];
  const f32x4 z = {0.f, 0.f, 0.f, 0.f};
#pragma unroll
  for (int i = 0; i < 8; ++i)
#pragma unroll
    for (int j = 0; j < 4; ++j) acc[i][j] = z;

  bf16x8 rA[4][2], rB[4][2];

  auto stage_tile = [&](int xbuf, int kt) {
    const size_t col = ((size_t)(t0 + kt) << 6) + sgrp;
#pragma unroll
    for (int u = 0; u < 4; ++u) {
      const unsigned short* src = (u < 2) ? Ab : Bb;
      const int rbase = ((u & 1) << 7) + srow;
      char* dst = lds + xbuf * 65536 + ((u & 2) << 14) + ((u & 1) << 14) + t * 16;
      gld_lds16(src + (size_t)rbase * K + col, dst);
      gld_lds16(src + (size_t)(rbase + 64) * K + col, dst + 8192);
    }
  };

  auto lda_f = [&](int xbuf, int i, int ks) -> bf16x8 {
    const int row = wm + (i << 4) + lr;
    const int pg = (ks * 4 + q) ^ (row & 7);
    return *(const bf16x8*)(lds + xbuf * 65536 + row * 128 + pg * 16);
  };
  auto ldb_f = [&](int xbuf, int j, int ks) -> bf16x8 {
    const int row = wn + (j << 4) + lr;
    const int pg = (ks * 4 + q) ^ (row & 7);
    return *(const bf16x8*)(lds + xbuf * 65536 + 32768 + row * 128 + pg * 16);
  };

  stage_tile(0, 0);
  if (np > 1) {
    stage_tile(1, 1);
    asm volatile("s_waitcnt vmcnt(8)" ::: "memory");
  } else {
    asm volatile("s_waitcnt vmcnt(0)" ::: "memory");
  }
  __builtin_amdgcn_s_barrier();

  for (int i = 0; i < np; ++i) {
    const int buf = i & 1;
    const bool st = (i + 2 < np);
    DS_A(buf, 0);
    DS_B(buf, 0);
    PHASE_SYNC();
    __builtin_amdgcn_s_setprio(1);
    MFMA_Q(0, 0);
    PHASE_END();
    DS_B(buf, 1);
    PHASE_SYNC();
    __builtin_amdgcn_s_setprio(1);
    MFMA_Q(0, 1);
    PHASE_END();
    DS_A(buf, 1);
    PHASE_SYNC();
    __builtin_amdgcn_s_setprio(1);
    MFMA_Q(1, 0);
    PHASE_END();
    if (st) {
      stage_tile(buf, i + 2);
      asm volatile("s_waitcnt vmcnt(8)" ::: "memory");
    } else {
      asm volatile("s_waitcnt vmcnt(0)" ::: "memory");
    }
    __builtin_amdgcn_s_barrier();
    __builtin_amdgcn_sched_barrier(0);
    __builtin_amdgcn_s_setprio(1);
    MFMA_Q(1, 1);
    __builtin_amdgcn_s_setprio(0);
  }

  float* Cb = Cpart + (size_t)s * MPAD * Ntot +
              (size_t)(bm * 256 + wm) * Ntot + bn * 256 + wn;
#pragma unroll
  for (int i = 0; i < 8; ++i)
#pragma unroll
    for (int j = 0; j < 4; ++j)
#pragma unroll
      for (int r = 0; r < 4; ++r)
        Cb[(size_t)(i * 16 + q * 4 + r) * Ntot + j * 16 + lr] = acc[i][j][r];
}

// ---------------------------------------------------------------------------
// gemm256s_bf16 (R9): SPLIT GEMM, 1-tile-deep pipelined schedule.
// BM=128 x BN=256 x BK=32, 8 waves (2Mx4N), each wave 64x64 out.
// LDS buf (49152B): Ah@0 (8K), Al@8192, Bh@16384 (16K), Bl@32768; dbuf=96KB.
// Per K-tile: 16 ds_read_b128 (issued 1 tile AHEAD into alternate reg set,
// drain under 48 MFMA), 6 gld_lds16 (counted vmcnt(6), 2 tiles ahead).
// R8 swizzle: pg = q ^ ((row>>1)&3), both staging source and reads.
// Accumulation per acc[i][j] per K-step: +AhBh, +AhBl, +AlBh (== old).
// ---------------------------------------------------------------------------
#define S_LOADSET(XB, SUF) do { \
  _Pragma("unroll") \
  for (int k_ = 0; k_ < 4; ++k_) { \
    aH##SUF[k_] = s_lda((XB), 0, k_); \
    aL##SUF[k_] = s_lda((XB), 1, k_); \
    bH##SUF[k_] = s_ldb((XB), 0, k_); \
    bL##SUF[k_] = s_ldb((XB), 1, k_); \
  } } while (0)

#define S_MFMASET(SUF) do { \
  _Pragma("unroll") \
  for (int i_ = 0; i_ < 4; ++i_) { \
    _Pragma("unroll") \
    for (int j_ = 0; j_ < 4; ++j_) { \
      f32x4* a_ = &acc[i_][j_]; \
      *a_ = __builtin_amdgcn_mfma_f32_16x16x32_bf16(aH##SUF[i_], bH##SUF[j_], *a_, 0, 0, 0); \
      *a_ = __builtin_amdgcn_mfma_f32_16x16x32_bf16(aH##SUF[i_], bL##SUF[j_], *a_, 0, 0, 0); \
      *a_ = __builtin_amdgcn_mfma_f32_16x16x32_bf16(aL##SUF[i_], bH##SUF[j_], *a_, 0, 0, 0); \
    } } } while (0)

// One pipelined tile. CUR/OTH are LITERAL 0/1 (static reg-set selection).
// Entering: set[CUR] holds tile I's fragments (loaded last iteration);
//           buf[CUR] holds tile I's LDS data (all reads of it drained);
//           buf[CUR^1] has tile I+1's staging in flight (<=6 + maybe 6 more).
#define S_TILE(I, CUR, OTH) do { \
  const bool st_ = ((I) + 2 < np); \
  if (st_) { \
    stage_tile((CUR), (I) + 2); \
    asm volatile("s_waitcnt vmcnt(6)" ::: "memory"); \
  } else { \
    asm volatile("s_waitcnt vmcnt(0)" ::: "memory"); \
  } \
  __builtin_amdgcn_s_barrier(); \
  if ((I) + 1 < np) { S_LOADSET((CUR) ^ 1, OTH); } \
  __builtin_amdgcn_s_setprio(1); \
  S_MFMASET(CUR); \
  __builtin_amdgcn_s_setprio(0); \
  asm volatile("s_waitcnt lgkmcnt(0)" ::: "memory"); \
  __builtin_amdgcn_sched_barrier(0); \
  __builtin_amdgcn_s_barrier(); \
} while (0)

__global__ __launch_bounds__(512, 2)
void gemm256s_bf16(const unsigned short* __restrict__ Ah,
                   const unsigned short* __restrict__ Al,
                   const unsigned short* __restrict__ Bh,
                   const unsigned short* __restrict__ Bl,
                   float* __restrict__ Cpart,
                   int Ntot, int K, int tilesTotal)
{
  extern __shared__ char lds[];
  const int t = threadIdx.x;
  const int ntile = Ntot >> 8;                 // N-tiles of 256
  const int bm = blockIdx.x / ntile;           // M-tiles of 128
  const int bn = blockIdx.x % ntile;
  const int s = blockIdx.y;
  const int S = gridDim.y;
  const int qp = tilesTotal / S, rp = tilesTotal % S;
  const int t0 = s * qp + (s < rp ? s : rp);
  const int np = qp + (s < rp ? 1 : 0);

  const unsigned short* Ahb = Ah + (size_t)bm * 128 * K;
  const unsigned short* Alb = Al + (size_t)bm * 128 * K;
  const unsigned short* Bhb = Bh + (size_t)bn * 256 * K;
  const unsigned short* Blb = Bl + (size_t)bn * 256 * K;

  // staging: 64B rows, 4 threads/row; physical slot (row, pg=t&3) holds
  // logical group (t&3)^((row>>1)&3) -> pre-swizzled global source column.
  const int srow = t >> 2;                              // 0..127
  const int sgrp = ((t & 3) ^ ((srow >> 1) & 3)) << 3;  // R8 swizzle

  const int lane = t & 63;
  const int wv = t >> 6;
  const int wm = (wv >> 2) << 6;   // 0 / 64
  const int wn = (wv & 3) << 6;    // 0 / 64 / 128 / 192
  const int lr = lane & 15;
  const int q = lane >> 4;

  f32x4 acc[4][4];
  const f32x4 z = {0.f, 0.f, 0.f, 0.f};
#pragma unroll
  for (int i = 0; i < 4; ++i)
#pragma unroll
    for (int j = 0; j < 4; ++j) acc[i][j] = z;

  // Two full fragment sets (64 VGPR each), statically indexed (rule #20).
  bf16x8 aH0[4], aL0[4], bH0[4], bL0[4];
  bf16x8 aH1[4], aL1[4], bH1[4], bL1[4];

  // 6 gld_lds16 per thread per K-tile
  auto stage_tile = [&](int xbuf, int kt) {
    const size_t col = ((size_t)(t0 + kt) << 5) + sgrp;
    char* base = lds + xbuf * 49152;
    gld_lds16(Ahb + (size_t)srow * K + col, base + t * 16);
    gld_lds16(Alb + (size_t)srow * K + col, base + 8192 + t * 16);
    gld_lds16(Bhb + (size_t)srow * K + col, base + 16384 + t * 16);
    gld_lds16(Bhb + (size_t)(srow + 128) * K + col, base + 16384 + 8192 + t * 16);
    gld_lds16(Blb + (size_t)srow * K + col, base + 32768 + t * 16);
    gld_lds16(Blb + (size_t)(srow + 128) * K + col, base + 32768 + 8192 + t * 16);
  };

  auto s_lda = [&](int xbuf, int pl, int i) -> bf16x8 {
    const int row = wm + (i << 4) + lr;          // 0..127
    const int pg = q ^ ((row >> 1) & 3);
    return *(const bf16x8*)(lds + xbuf * 49152 + pl * 8192 + row * 64 + pg * 16);
  };
  auto s_ldb = [&](int xbuf, int pl, int j) -> bf16x8 {
    const int row = wn + (j << 4) + lr;          // 0..255
    const int pg = q ^ ((row >> 1) & 3);
    return *(const bf16x8*)(lds + xbuf * 49152 + 16384 + pl * 16384 + row * 64 + pg * 16);
  };

  // prologue: tile0 -> buf0, tile1 -> buf1; tile0 reads into set0
  stage_tile(0, 0);
  if (np > 1) {
    stage_tile(1, 1);
    asm volatile("s_waitcnt vmcnt(6)" ::: "memory");   // tile 0 landed
  } else {
    asm volatile("s_waitcnt vmcnt(0)" ::: "memory");
  }
  __builtin_amdgcn_s_barrier();
  S_LOADSET(0, 0);
  asm volatile("s_waitcnt lgkmcnt(0)" ::: "memory");   // set0 ready; buf0
  __builtin_amdgcn_sched_barrier(0);                   // reads globally done
  __builtin_amdgcn_s_barrier();                        // after this barrier

  int i = 0;
  for (; i + 2 <= np; i += 2) {
    S_TILE(i, 0, 1);
    S_TILE(i + 1, 1, 0);
  }
  if (i < np) S_TILE(i, 0, 1);

  float* Cb = Cpart + (size_t)s * MPAD * Ntot +
              (size_t)(bm * 128 + wm) * Ntot + bn * 256 + wn;
#pragma unroll
  for (int ii = 0; ii < 4; ++ii)
#pragma unroll
    for (int jj = 0; jj < 4; ++jj)
#pragma unroll
      for (int r = 0; r < 4; ++r)
        Cb[(size_t)(ii * 16 + q * 4 + r) * Ntot + jj * 16 + lr] = acc[ii][jj][r];
}

// ---------------------------------------------------------------------------
// Epilogue (x4 vectorized): v = relu(sum_s partial + bias), emit bf16 hi[,lo].
// ---------------------------------------------------------------------------
__global__ __launch_bounds__(256)
void epilogue_kernel(const float* __restrict__ Cpart, int S, int H, int Nh,
                     const float* __restrict__ bias,
                     unsigned short* __restrict__ ohi,
                     unsigned short* __restrict__ olo, int flags)
{
  size_t total = (size_t)H * MPAD * Nh;
  size_t idx = ((size_t)blockIdx.x * 256 + threadIdx.x) * 4;
  if (idx >= total) return;
  int n = (int)(idx % Nh);
  int h = (int)(idx / ((size_t)MPAD * Nh));
  f32x4 v = *(const f32x4*)&bias[(size_t)h * Nh + n];
  for (int s = 0; s < S; ++s) v += *(const f32x4*)&Cpart[(size_t)s * total + idx];
  u16x4 hi, lo;
#pragma unroll
  for (int j = 0; j < 4; ++j) {
    float x = fmaxf(v[j], 0.f);
    hi[j] = f2bf(x);
    lo[j] = f2bf(x - bf2f(hi[j]));
  }
  *(u16x4*)&ohi[idx] = hi;
  if (flags & 4) *(u16x4*)&olo[idx] = lo;
}

// Epilogue for stage-2 fused fc1 (N=3072): partials [s][1024][3072],
// de-interleave into h1_hi[h][1024][1024]. bias = fc1_b (3x1024 contiguous).
__global__ __launch_bounds__(256)
void epilogue_fc1_s2(const float* __restrict__ Cpart, int S,
                     const float* __restrict__ bias,
                     unsigned short* __restrict__ ohi)
{
  const size_t total = (size_t)MPAD * 3072;
  size_t idx = ((size_t)blockIdx.x * 256 + threadIdx.x) * 4;
  if (idx >= total) return;
  int n = (int)(idx % 3072);
  int m = (int)(idx / 3072);
  f32x4 v = *(const f32x4*)&bias[n];
  for (int s = 0; s < S; ++s) v += *(const f32x4*)&Cpart[(size_t)s * total + idx];
  u16x4 hi;
#pragma unroll
  for (int j = 0; j < 4; ++j) hi[j] = f2bf(fmaxf(v[j], 0.f));
  int h = n >> 10;
  *(u16x4*)&ohi[((size_t)h * MPAD + m) * 1024 + (n & 1023)] = hi;
}

// ---------------------------------------------------------------------------
// Transpose + fp32->bf16 hi/lo: W[H][K][N] -> T[H][N][K].
// ---------------------------------------------------------------------------
__global__ __launch_bounds__(256)
void transpose_convert(const float* __restrict__ W,
                       unsigned short* __restrict__ Thi,
                       unsigned short* __restrict__ Tlo,
                       int K, int N, int loHeads)
{
  __shared__ float tile[32][260];
  int kb = blockIdx.x * 256;
  int nb = blockIdx.y * 32;
  int h = blockIdx.z;
  const float* Wb = W + (size_t)h * K * N + (size_t)kb * N + nb;
  int tn = threadIdx.x & 31;
  int tk = threadIdx.x >> 5;
#pragma unroll
  for (int i = 0; i < 32; ++i) {
    int k = tk + i * 8;
    tile[tn][k] = Wb[(size_t)k * N + tn];
  }
  __syncthreads();
  bool wlo = h < loHeads;
  int l = threadIdx.x & 63;
  int ng = threadIdx.x >> 6;
  size_t ob = (size_t)h * N * K + (size_t)nb * K + kb;
#pragma unroll
  for (int i = 0; i < 8; ++i) {
    int n = ng + i * 4;
    f32x4 v = *(const f32x4*)&tile[n][4 * l];
    u16x4 hi;
#pragma unroll
    for (int j = 0; j < 4; ++j) hi[j] = f2bf(v[j]);
    *(u16x4*)&Thi[ob + (size_t)n * K + 4 * l] = hi;
    if (wlo) {
      u16x4 lo;
#pragma unroll
      for (int j = 0; j < 4; ++j) lo[j] = f2bf(v[j] - bf2f(hi[j]));
      *(u16x4*)&Tlo[ob + (size_t)n * K + 4 * l] = lo;
    }
  }
}

// cls_w (3,1024,81) -> w3t (3,128,1024) bf16, rows 81..127 zero. grid (128,3).
__global__ void transpose_cls(const float* __restrict__ W, unsigned short* __restrict__ T)
{
  int n = blockIdx.x, h = blockIdx.y, t = threadIdx.x;
  size_t ob = ((size_t)h * 128 + n) * 1024;
  if (n < 81) {
    for (int k = t; k < 1024; k += 256)
      T[ob + k] = f2bf(W[((size_t)h * 1024 + k) * 81 + n]);
  } else {
    for (int k = t; k < 1024; k += 256) T[ob + k] = 0;
  }
}

// ---------------------------------------------------------------------------
// Pyramid ROI-align: one block per roi; 64 channel-quads x 4 position groups.
// ---------------------------------------------------------------------------
__global__ void roi_align_kernel(const float* __restrict__ rois,
                                 const float* __restrict__ P2, const float* __restrict__ P3,
                                 const float* __restrict__ P4, const float* __restrict__ P5,
                                 unsigned short* __restrict__ phi,
                                 unsigned short* __restrict__ plo, int writeLo)
{
  int m = blockIdx.x;
  int t = threadIdx.x;
  int c = (t & 63) * 4;
  int pg = t >> 6;  // 0..3
  const float* rp = rois + m * 4;
  float y1 = rp[0], x1 = rp[1], y2 = rp[2], x2 = rp[3];
  float hh = y2 - y1, ww = x2 - x1;
  float a = sqrtf(fmaxf(hh * ww, 1e-6f)) / 224.0f;
  float lvl = floorf(4.0f + log2f(a));
  lvl = fminf(fmaxf(lvl, 2.0f), 5.0f);
  int i = (int)lvl - 2;
  const float* f = (i == 0) ? P2 : (i == 1) ? P3 : (i == 2) ? P4 : P5;
  int H = 256 >> i;
  float stride = (float)(4 << i);
  float sy1 = y1 / stride, sx1 = x1 / stride;
  float dy = y2 / stride - sy1, dx = x2 / stride - sx1;
  size_t base = (size_t)m * K1 + c;
  for (int p = pg; p < 49; p += 4) {
    int py = p / 7, px = p % 7;
    float ys = sy1 + ((py + 0.5f) / 7.0f) * dy;
    float xs = sx1 + ((px + 0.5f) / 7.0f) * dx;
    float y0f = fminf(fmaxf(floorf(ys), 0.0f), (float)(H - 1));
    float x0f = fminf(fmaxf(floorf(xs), 0.0f), (float)(H - 1));
    int y0 = (int)y0f, x0 = (int)x0f;
    int y1i = min(y0 + 1, H - 1), x1i = min(x0 + 1, H - 1);
    float wy = fminf(fmaxf(ys - y0f, 0.0f), 1.0f);
    float wx = fminf(fmaxf(xs - x0f, 0.0f), 1.0f);
    f32x4 v00 = *(const f32x4*)(f + ((size_t)y0 * H + x0) * 256 + c);
    f32x4 v01 = *(const f32x4*)(f + ((size_t)y0 * H + x1i) * 256 + c);
    f32x4 v10 = *(const f32x4*)(f + ((size_t)y1i * H + x0) * 256 + c);
    f32x4 v11 = *(const f32x4*)(f + ((size_t)y1i * H + x1i) * 256 + c);
    float w00 = (1.f - wy) * (1.f - wx), w01 = (1.f - wy) * wx;
    float w10 = wy * (1.f - wx), w11 = wy * wx;
    f32x4 v = v00 * w00 + v01 * w01 + v10 * w10 + v11 * w11;
    u16x4 hi;
#pragma unroll
    for (int j = 0; j < 4; ++j) hi[j] = f2bf(v[j]);
    *(u16x4*)&phi[base + p * 256] = hi;
    if (writeLo) {
      u16x4 lo;
#pragma unroll
      for (int j = 0; j < 4; ++j) lo[j] = f2bf(v[j] - bf2f(hi[j]));
      *(u16x2*)&plo[base + p * 256] = *(u16x2*)&lo;
      *(u16x2*)&plo[base + p * 256 + 2] = *((u16x2*)&lo + 1);
    }
  }
}

// ---------------------------------------------------------------------------
// FUSED fc2-epilogue + reg head + delta2bbox (stages 0/1).
// ---------------------------------------------------------------------------
__global__ void reg_delta_kernel(const float* __restrict__ Cpart, int S,
                                 const float* __restrict__ fb,
                                 const float* __restrict__ rw, const float* __restrict__ rb,
                                 const float* __restrict__ rin, float* __restrict__ rout)
{
  int m = blockIdx.x, t = threadIdx.x;
  float s0 = 0, s1 = 0, s2 = 0, s3 = 0;
  for (int n = t; n < 1024; n += 256) {
    float v = fb[n];
    for (int s = 0; s < S; ++s) v += Cpart[((size_t)s * 1024 + m) * 1024 + n];
    v = fmaxf(v, 0.f);
    const float* w = rw + (size_t)n * 4;
    s0 += v * w[0]; s1 += v * w[1]; s2 += v * w[2]; s3 += v * w[3];
  }
#pragma unroll
  for (int o = 32; o > 0; o >>= 1) {
    s0 += __shfl_xor(s0, o, 64);
    s1 += __shfl_xor(s1, o, 64);
    s2 += __shfl_xor(s2, o, 64);
    s3 += __shfl_xor(s3, o, 64);
  }
  __shared__ float part[4][4];
  int w = t >> 6;
  if ((t & 63) == 0) { part[w][0] = s0; part[w][1] = s1; part[w][2] = s2; part[w][3] = s3; }
  __syncthreads();
  if (t == 0) {
    float d0 = (part[0][0] + part[1][0] + part[2][0] + part[3][0] + rb[0]) * 0.1f;
    float d1 = (part[0][1] + part[1][1] + part[2][1] + part[3][1] + rb[1]) * 0.1f;
    float d2 = (part[0][2] + part[1][2] + part[2][2] + part[3][2] + rb[2]) * 0.2f;
    float d3 = (part[0][3] + part[1][3] + part[2][3] + part[3][3] + rb[3]) * 0.2f;
    const float* r = rin + m * 4;
    float y1 = r[0], x1 = r[1], y2 = r[2], x2 = r[3];
    float h = y2 - y1, wd = x2 - x1;
    float cy = y1 + 0.5f * h + d0 * h;
    float cx = x1 + 0.5f * wd + d1 * wd;
    float nh = h * expf(d2);
    float nw = wd * expf(d3);
    float* ro = rout + m * 4;
    ro[0] = fminf(fmaxf(cy - 0.5f * nh, 0.f), 1024.f);
    ro[1] = fminf(fmaxf(cx - 0.5f * nw, 0.f), 1024.f);
    ro[2] = fminf(fmaxf(cy + 0.5f * nh, 0.f), 1024.f);
    ro[3] = fminf(fmaxf(cx + 0.5f * nw, 0.f), 1024.f);
  }
}

// ---------------------------------------------------------------------------
// FUSED cls-epilogue + softmax + 3-head average.
// ---------------------------------------------------------------------------
__global__ void softmax_avg_kernel(const float* __restrict__ Cpart, int S,
                                   const float* __restrict__ cls_b,
                                   float* __restrict__ out)
{
  int m = blockIdx.x, t = threadIdx.x;
  __shared__ float sh[128];
  float pacc = 0.0f;
  for (int h = 0; h < 3; ++h) {
    float x = -3.0e38f;
    if (t < 81) {
      x = cls_b[h * 81 + t];
      for (int s = 0; s < S; ++s)
        x += Cpart[((size_t)(s * 3 + h) * 1024 + m) * 128 + t];
    }
    sh[t] = x; __syncthreads();
    for (int o = 64; o > 0; o >>= 1) { if (t < o) sh[t] = fmaxf(sh[t], sh[t + o]); __syncthreads(); }
    float mx = sh[0]; __syncthreads();
    float e = (t < 81) ? expf(x - mx) : 0.0f;
    sh[t] = e; __syncthreads();
    for (int o = 64; o > 0; o >>= 1) { if (t < o) sh[t] += sh[t + o]; __syncthreads(); }
    float sum = sh[0]; __syncthreads();
    pacc += e / sum;
  }
  if (t < 81) out[(size_t)m * 81 + t] = pacc / 3.0f;
}

// ===========================================================================
extern "C" void kernel_launch(void* const* d_in, const int* in_sizes, int n_in,
                              void* d_out, int out_size, void* d_ws, size_t ws_size,
                              hipStream_t stream)
{
  const float* P2 = (const float*)d_in[0];
  const float* P3 = (const float*)d_in[1];
  const float* P4 = (const float*)d_in[2];
  const float* P5 = (const float*)d_in[3];
  const float* rois = (const float*)d_in[4];
  const float* fc1_w = (const float*)d_in[5];
  const float* fc1_b = (const float*)d_in[6];
  const float* fc2_w = (const float*)d_in[7];
  const float* fc2_b = (const float*)d_in[8];
  const float* cls_w = (const float*)d_in[9];
  const float* cls_b = (const float*)d_in[10];
  const float* reg_w = (const float*)d_in[11];
  const float* reg_b = (const float*)d_in[12];
  float* out = (float*)d_out;

  char* ws = (char*)d_ws;
  size_t off = 0;
  auto alloc = [&](size_t b) -> char* {
    char* p = ws + off;
    off = (off + b + 255) & ~(size_t)255;
    return p;
  };
  unsigned short* w1t_hi = (unsigned short*)alloc(3ull * 1024 * K1 * 2);
  unsigned short* w2t_hi = (unsigned short*)alloc(3ull * 1024 * 1024 * 2);
  unsigned short* w2t_lo = (unsigned short*)alloc(2ull * 1024 * 1024 * 2);
  unsigned short* w3t    = (unsigned short*)alloc(3ull * 128 * 1024 * 2);
  unsigned short* phi    = (unsigned short*)alloc((size_t)MPAD * K1 * 2);
  unsigned short* plo    = (unsigned short*)alloc((size_t)MPAD * K1 * 2);
  unsigned short* h1_hi  = (unsigned short*)alloc(3ull * MPAD * 1024 * 2);
  unsigned short* h1_lo  = (unsigned short*)alloc((size_t)MPAD * 1024 * 2);
  unsigned short* h2_hi  = (unsigned short*)alloc(3ull * MPAD * 1024 * 2);
  float* r1              = (float*)alloc(16384);
  float* r2              = (float*)alloc(16384);
  // w1t_lo LAST: dead after stage 1, so stage-2 partials reuse it + tail.
  const size_t w1lo_bytes = 2ull * 1024 * K1 * 2;
  unsigned short* w1t_lo = (unsigned short*)alloc(w1lo_bytes);

  const size_t SLAB = (size_t)MPAD * 1024 * 4;  // 4 MiB per (s,h) slice
  size_t tail = (ws_size > off) ? (ws_size - off) : 0;

  // stages 0/1 partials in tail; R2-proven sweet spot S=8
  int S01 = (int)(tail / SLAB);
  if (S01 > 8) S01 = 8;
  if (S01 < 1) S01 = 1;
  float* cpart01 = (float*)(ws + off);
  // stage-2 partials alias w1t_lo + tail
  const int S2 = 4;
  float* cpart2 = (float*)w1t_lo;

  const int fc2Steps01 = (32 + S01 - 1) / S01;

  const long long hs1 = (long long)1024 * K1;
  const long long hs2 = (long long)1024 * 1024;

  dim3 b256(256);

  // --- weight conversion (per call) ---
  hipLaunchKernelGGL(transpose_convert, dim3(K1 / 256, 32, 3), b256, 0, stream,
                     fc1_w, w1t_hi, w1t_lo, K1, 1024, 2);
  hipLaunchKernelGGL(transpose_convert, dim3(4, 32, 3), b256, 0, stream,
                     fc2_w, w2t_hi, w2t_lo, 1024, 1024, 2);
  hipLaunchKernelGGL(transpose_cls, dim3(128, 3), b256, 0, stream, cls_w, w3t);
  hipMemsetAsync(phi + (size_t)NROI * K1, 0, (size_t)(MPAD - NROI) * K1 * 2, stream);
  hipMemsetAsync(plo + (size_t)NROI * K1, 0, (size_t)(MPAD - NROI) * K1 * 2, stream);

  // --- stages 0,1: split-precision path, deltas only ---
  for (int st = 0; st < 2; ++st) {
    const float* rin = (st == 0) ? rois : r1;
    float* rout = (st == 0) ? r1 : r2;
    hipLaunchKernelGGL(roi_align_kernel, dim3(NROI), b256, 0, stream,
                       rin, P2, P3, P4, P5, phi, plo, 1);
    // SPLIT fc1 on gemm256s: grid 32 x S01(=8) = 256 blocks = 1/CU.
    hipLaunchKernelGGL(gemm256s_bf16, dim3(32, S01), dim3(512), 98304, stream,
                       phi, plo,
                       w1t_hi + (size_t)st * hs1, w1t_lo + (size_t)st * hs1,
                       cpart01, 1024, K1, 392);
    hipLaunchKernelGGL(epilogue_kernel, dim3(1024), b256, 0, stream,
                       cpart01, S01, 1, 1024, fc1_b + st * 1024,
                       h1_hi, h1_lo, 4);
    hipLaunchKernelGGL((gemm_bf16<true>), dim3(64, S01, 1), b256, 0, stream,
                       h1_hi, h1_lo, 0LL,
                       w2t_hi + (size_t)st * hs2, w2t_lo + (size_t)st * hs2, 0LL,
                       cpart01, 1024, 1024, fc2Steps01);
    hipLaunchKernelGGL(reg_delta_kernel, dim3(NROI), b256, 0, stream,
                       cpart01, S01, fc2_b + st * 1024,
                       reg_w + (size_t)st * 1024 * 4, reg_b + st * 4,
                       rin, rout);
  }

  // --- stage 2 ---
  hipLaunchKernelGGL(roi_align_kernel, dim3(NROI), b256, 0, stream,
                     r2, P2, P3, P4, P5, phi, plo, 0);
  // fc1 for heads 0,1,2 as ONE fused GEMM: M=1024, N=3072 on gemm256_bf16.
  {
    const size_t SLAB3 = (size_t)MPAD * 3072 * 4;
    size_t availC2 = ws_size - (size_t)((char*)w1t_lo - ws);
    int S2f = 5;
    while (S2f > 1 && (size_t)S2f * SLAB3 > availC2) --S2f;
    hipLaunchKernelGGL(gemm256_bf16, dim3(48, S2f), dim3(512), 131072, stream,
                       phi, w1t_hi, cpart2, 3072, K1, 196);
    hipLaunchKernelGGL(epilogue_fc1_s2, dim3(3072), b256, 0, stream,
                       cpart2, S2f, fc1_b, h1_hi);
  }
  // fc2: heads batched via blockIdx.z on the 128^2 kernel.
  hipLaunchKernelGGL((gemm_bf16<false>), dim3(64, S2, 3), b256, 0, stream,
                     h1_hi, (const unsigned short*)0, hs2,
                     w2t_hi, (const unsigned short*)0, hs2,
                     cpart2, 1024, 1024, (32 + S2 - 1) / S2);
  hipLaunchKernelGGL(epilogue_kernel, dim3(3072), b256, 0, stream,
                     cpart2, S2, 3, 1024, fc2_b,
                     h2_hi, (unsigned short*)0, 0);
  // cls: N=128 (81 real + pad), S=8 -> 192 blocks, 4 steps
  hipLaunchKernelGGL((gemm_bf16<false>), dim3(8, 8, 3), b256, 0, stream,
                     h2_hi, (const unsigned short*)0, hs2,
                     w3t, (const unsigned short*)0, (long long)128 * 1024,
                     cpart2, 128, 1024, 4);
  hipLaunchKernelGGL(softmax_avg_kernel, dim3(NROI), dim3(128), 0, stream,
                     cpart2, 8, cls_b, out);
}